// Round 13
// baseline (827.965 us; speedup 1.0000x reference)
//
#include <hip/hip_runtime.h>
#include <math.h>

#define EF 128
#define NPTS 32768
#define KNN 8
#define MVOX 8192
#define GDIM 32
#define NVOXG (GDIM*GDIM*GDIM)

typedef __attribute__((ext_vector_type(8))) short bfrag;   // 8 x bf16
typedef __attribute__((ext_vector_type(4))) float f32x4;

__device__ __forceinline__ float lrelu(float x) { return x > 0.f ? x : 0.01f * x; }
__device__ __forceinline__ short f2b(float f) {            // fp32 -> bf16 (RNE)
    unsigned u = __float_as_uint(f);
    return (short)((u + 0x7fff + ((u >> 16) & 1)) >> 16);
}
__device__ __forceinline__ float b2f(short s) {
    return __uint_as_float(((unsigned)(unsigned short)s) << 16);
}
#define MFMA(a,b,c) __builtin_amdgcn_mfma_f32_16x16x32_bf16((a),(b),(c),0,0,0)
// LDS tile addressing: row-major 256B rows, XOR swizzle on byte bits 4-6
__device__ __forceinline__ int swz(int row, int bytecol) {
    return row * 256 + (bytecol ^ ((row & 7) << 4));
}

// ------- batched weight packing: n_layers x [W[k][col] -> [step][ct][lane][8] bf16] -------
__global__ void k_pack_w(const float* __restrict__ src, short* __restrict__ dst,
                         int K_real, int n_steps, int k_str, int c_str,
                         int src_ls, int dst_ls, int n_layers) {
    int t = blockIdx.x * 256 + threadIdx.x;
    int per = n_steps * 4096;
    if (t >= n_layers * per) return;
    int layer = t / per;
    int u = t - layer * per;
    int r = u & 7, l = (u >> 3) & 63, ct = (u >> 9) & 7, s = u >> 12;
    int k = s * 32 + (l >> 4) * 8 + r;
    int col = ct * 16 + (l & 15);
    float v = (k < K_real) ? src[(size_t)layer * src_ls + (size_t)k * k_str + (size_t)col * c_str] : 0.f;
    dst[(size_t)layer * dst_ls + u] = f2b(v);
}
// conv3x3x3 weights, 8 layers: [o][ci][27] -> [tap*4+cc][ct][lane][8]
__global__ void k_pack_wc1(const float* __restrict__ src, short* __restrict__ dst) {
    int g = blockIdx.x;
    int layer = g / 1728;
    int t = (g - layer * 1728) * 256 + threadIdx.x;
    if (t >= 108 * 4096) return;
    int r = t & 7, l = (t >> 3) & 63, ct = (t >> 9) & 7, s = t >> 12;
    int tap = s >> 2;
    int ci = (s & 3) * 32 + (l >> 4) * 8 + r;
    int col = ct * 16 + (l & 15);
    dst[(size_t)layer * 442368 + t] =
        f2b(src[(size_t)layer * 442368 + ((size_t)col * 128 + ci) * 27 + tap]);
}

// ============ template: block = 128 gather-rows (16 out rows), 8 waves 2Mx4N, fused res + U ============

// ---------------- pc_conv_first: MFMA phase-1 + GEMM2 + pool + fused res0 + U0 epilogue ----------------
__global__ __launch_bounds__(512) void k_pcfirst(
    const float* __restrict__ xyz, const short* __restrict__ w1p, const float* __restrict__ b1,
    const short* __restrict__ w2p, const float* __restrict__ b2,
    const short* __restrict__ rw1p, const float* __restrict__ rb1,
    const short* __restrict__ rw2p, const float* __restrict__ rb2,
    const short* __restrict__ wu, short* __restrict__ Uout,
    float* __restrict__ out32, short* __restrict__ out16) {
    __shared__ __align__(16) char tb[32768];
    int wid = threadIdx.x >> 6, lane = threadIdx.x & 63, lrow = lane & 15, lq = lane >> 4;
    int wm = wid >> 2, wn = wid & 3;
    int rowbase = blockIdx.x * 128;
    f32x4 zv = {0.f, 0.f, 0.f, 0.f};
    // ---- phase 1: 3->128 via 1-k-step MFMA ----
    {
        f32x4 acc1[4][2];
        #pragma unroll
        for (int rt = 0; rt < 4; ++rt) { acc1[rt][0] = zv; acc1[rt][1] = zv; }
        bfrag Bv[2];
        #pragma unroll
        for (int ct = 0; ct < 2; ++ct) Bv[ct] = ((const bfrag*)w1p)[(wn * 2 + ct) * 64 + lane];
        #pragma unroll
        for (int rt = 0; rt < 4; ++rt) {
            bfrag a4;
            #pragma unroll
            for (int r = 0; r < 8; ++r) a4[r] = 0;
            if (lq == 0) {
                int gr = rowbase + wm * 64 + rt * 16 + lrow;
                a4[0] = f2b(xyz[gr * 3]); a4[1] = f2b(xyz[gr * 3 + 1]); a4[2] = f2b(xyz[gr * 3 + 2]);
            }
            #pragma unroll
            for (int ct = 0; ct < 2; ++ct) acc1[rt][ct] = MFMA(a4, Bv[ct], acc1[rt][ct]);
        }
        float bb1[2];
        #pragma unroll
        for (int ct = 0; ct < 2; ++ct) bb1[ct] = b1[wn * 32 + ct * 16 + lrow];
        #pragma unroll
        for (int rt = 0; rt < 4; ++rt)
            #pragma unroll
            for (int ct = 0; ct < 2; ++ct)
                #pragma unroll
                for (int r = 0; r < 4; ++r) {
                    int row = wm * 64 + rt * 16 + lq * 4 + r, col = wn * 32 + ct * 16 + lrow;
                    *(short*)(tb + swz(row, col * 2)) = f2b(lrelu(acc1[rt][ct][r] + bb1[ct]));
                }
    }
    __syncthreads();
    // ---- GEMM2 + pool ----
    float bb2[2];
    #pragma unroll
    for (int ct = 0; ct < 2; ++ct) bb2[ct] = b2[wn * 32 + ct * 16 + lrow];
    f32x4 acc[4][2];
    #pragma unroll
    for (int rt = 0; rt < 4; ++rt) { acc[rt][0] = zv; acc[rt][1] = zv; }
    const bfrag* bp2 = (const bfrag*)w2p;
    #pragma unroll
    for (int s = 0; s < 4; ++s) {
        bfrag Bv[2];
        #pragma unroll
        for (int ct = 0; ct < 2; ++ct) Bv[ct] = bp2[(s * 8 + wn * 2 + ct) * 64 + lane];
        bfrag av[4];
        #pragma unroll
        for (int rt = 0; rt < 4; ++rt) {
            int row = wm * 64 + rt * 16 + lrow;
            av[rt] = *(const bfrag*)(tb + swz(row, s * 64 + lq * 16));
        }
        #pragma unroll
        for (int ct = 0; ct < 2; ++ct)
            #pragma unroll
            for (int rt = 0; rt < 4; ++rt) acc[rt][ct] = MFMA(av[rt], Bv[ct], acc[rt][ct]);
    }
    float pv[4][2];
    #pragma unroll
    for (int rt = 0; rt < 4; ++rt)
        #pragma unroll
        for (int ct = 0; ct < 2; ++ct) {
            float m = -INFINITY;
            #pragma unroll
            for (int r = 0; r < 4; ++r) m = fmaxf(m, acc[rt][ct][r] + bb2[ct]);
            m = fmaxf(m, __shfl_xor(m, 16, 64));
            pv[rt][ct] = lrelu(m);
        }
    // ---- pooled x -> LDS tiles ----
    __syncthreads();
    float* xf = (float*)(tb + 4096);            // [16][130]
    char*  tres = tb + 12544;                   // 16-row swizzled bf16 tile
    if ((lq & 1) == 0) {
        #pragma unroll
        for (int rt = 0; rt < 4; ++rt)
            #pragma unroll
            for (int ct = 0; ct < 2; ++ct) {
                int row = wm * 8 + rt * 2 + (lq >> 1), col = wn * 32 + ct * 16 + lrow;
                *(short*)(tb + swz(row, col * 2)) = f2b(pv[rt][ct]);
                xf[row * 130 + col] = pv[rt][ct];
            }
    }
    __syncthreads();
    // ---- fused res: GEMM1 ----
    {
        f32x4 r1 = zv;
        #pragma unroll
        for (int s = 0; s < 4; ++s) {
            bfrag B = ((const bfrag*)rw1p)[(s * 8 + wid) * 64 + lane];
            bfrag a = *(const bfrag*)(tb + swz(lrow, s * 64 + lq * 16));
            r1 = MFMA(a, B, r1);
        }
        float rb1v = rb1[wid * 16 + lrow];
        #pragma unroll
        for (int r = 0; r < 4; ++r) {
            int row = lq * 4 + r;
            *(short*)(tres + swz(row, (wid * 16 + lrow) * 2)) = f2b(lrelu(r1[r] + rb1v));
        }
    }
    __syncthreads();
    {
        f32x4 r2 = zv;
        #pragma unroll
        for (int s = 0; s < 4; ++s) {
            bfrag B = ((const bfrag*)rw2p)[(s * 8 + wid) * 64 + lane];
            bfrag a = *(const bfrag*)(tres + swz(lrow, s * 64 + lq * 16));
            r2 = MFMA(a, B, r2);
        }
        float rb2v = rb2[wid * 16 + lrow];
        int p0 = blockIdx.x * 16;
        #pragma unroll
        for (int r = 0; r < 4; ++r) {
            int row = lq * 4 + r, col = wid * 16 + lrow;
            float v = lrelu(r2[r] + rb2v + xf[row * 130 + col]);
            size_t o = (size_t)(p0 + row) * 128 + col;
            if (out16) out16[o] = f2b(v);
            if (out32) out32[o] = v;
            *(short*)(tb + swz(row, col * 2)) = f2b(v);   // stash for U-GEMM
        }
    }
    __syncthreads();
    // ---- U epilogue: U = out @ W1next[0:128] ----
    if (wu) {
        f32x4 ua = zv;
        #pragma unroll
        for (int s = 0; s < 4; ++s) {
            bfrag B = ((const bfrag*)wu)[(s * 8 + wid) * 64 + lane];
            bfrag a = *(const bfrag*)(tb + swz(lrow, s * 64 + lq * 16));
            ua = MFMA(a, B, ua);
        }
        int p0 = blockIdx.x * 16;
        #pragma unroll
        for (int r = 0; r < 4; ++r)
            Uout[(size_t)(p0 + lq * 4 + r) * 128 + wid * 16 + lrow] = f2b(ua[r]);
    }
}

// ---------------- pc_conv: gather-U + xyz-VALU + 128->128 GEMM2 + pool + fused res + U ----------------
__global__ __launch_bounds__(512) void k_pcconv(
    const short* __restrict__ Uin, const int* __restrict__ idx, const float* __restrict__ xyz,
    const float* __restrict__ W1raw, const float* __restrict__ b1,
    const short* __restrict__ w2p, const float* __restrict__ b2,
    const short* __restrict__ rw1p, const float* __restrict__ rb1,
    const short* __restrict__ rw2p, const float* __restrict__ rb2,
    const short* __restrict__ wu, short* __restrict__ Uout,
    float* __restrict__ out32, short* __restrict__ out16) {
    __shared__ __align__(16) char tb[32768];
    int wid = threadIdx.x >> 6, lane = threadIdx.x & 63, lrow = lane & 15, lq = lane >> 4;
    int wm = wid >> 2, wn = wid & 3;
    int rowbase = blockIdx.x * 128;
    f32x4 zv = {0.f, 0.f, 0.f, 0.f};
    // ---- phase 1: t = lrelu(U[idx] + xyz @ W1[128:131] + b1) on VALU, direct to t-tile ----
    {
        int srow = threadIdx.x >> 2;
        int cb = (threadIdx.x & 3) * 32;
        int grow = rowbase + srow;
        int nb = idx[grow];
        const bfrag* up = (const bfrag*)(Uin + (size_t)nb * 128) + (cb >> 3);
        bfrag u0 = up[0], u1 = up[1], u2 = up[2], u3 = up[3];
        float x0 = xyz[grow * 3], y0 = xyz[grow * 3 + 1], z0 = xyz[grow * 3 + 2];
        const f32x4* Wx = (const f32x4*)(W1raw + 128 * 128) + (cb >> 2);
        const f32x4* Wy = (const f32x4*)(W1raw + 129 * 128) + (cb >> 2);
        const f32x4* Wz = (const f32x4*)(W1raw + 130 * 128) + (cb >> 2);
        const f32x4* Bb = (const f32x4*)b1 + (cb >> 2);
        #pragma unroll
        for (int j0 = 0; j0 < 4; ++j0) {
            bfrag uj = (j0 == 0) ? u0 : (j0 == 1) ? u1 : (j0 == 2) ? u2 : u3;
            f32x4 wxa = Wx[j0 * 2], wxb = Wx[j0 * 2 + 1];
            f32x4 wya = Wy[j0 * 2], wyb = Wy[j0 * 2 + 1];
            f32x4 wza = Wz[j0 * 2], wzb = Wz[j0 * 2 + 1];
            f32x4 bba = Bb[j0 * 2], bbb = Bb[j0 * 2 + 1];
            bfrag v;
            #pragma unroll
            for (int j = 0; j < 8; ++j) {
                float wxv = (j < 4) ? wxa[j & 3] : wxb[j & 3];
                float wyv = (j < 4) ? wya[j & 3] : wyb[j & 3];
                float wzv = (j < 4) ? wza[j & 3] : wzb[j & 3];
                float bbv = (j < 4) ? bba[j & 3] : bbb[j & 3];
                float s = b2f(uj[j]) + x0 * wxv + y0 * wyv + z0 * wzv + bbv;
                v[j] = f2b(lrelu(s));
            }
            *(bfrag*)(tb + swz(srow, (cb + j0 * 8) * 2)) = v;
        }
    }
    __syncthreads();
    // ---- GEMM2 + pool ----
    float bb2[2];
    #pragma unroll
    for (int ct = 0; ct < 2; ++ct) bb2[ct] = b2[wn * 32 + ct * 16 + lrow];
    f32x4 acc2[4][2];
    #pragma unroll
    for (int rt = 0; rt < 4; ++rt) { acc2[rt][0] = zv; acc2[rt][1] = zv; }
    const bfrag* bp2 = (const bfrag*)w2p;
    #pragma unroll
    for (int s = 0; s < 4; ++s) {
        bfrag Bv[2];
        #pragma unroll
        for (int ct = 0; ct < 2; ++ct) Bv[ct] = bp2[(s * 8 + wn * 2 + ct) * 64 + lane];
        bfrag av[4];
        #pragma unroll
        for (int rt = 0; rt < 4; ++rt) {
            int row = wm * 64 + rt * 16 + lrow;
            av[rt] = *(const bfrag*)(tb + swz(row, s * 64 + lq * 16));
        }
        #pragma unroll
        for (int ct = 0; ct < 2; ++ct)
            #pragma unroll
            for (int rt = 0; rt < 4; ++rt) acc2[rt][ct] = MFMA(av[rt], Bv[ct], acc2[rt][ct]);
    }
    float pv[4][2];
    #pragma unroll
    for (int rt = 0; rt < 4; ++rt)
        #pragma unroll
        for (int ct = 0; ct < 2; ++ct) {
            float m = -INFINITY;
            #pragma unroll
            for (int r = 0; r < 4; ++r) m = fmaxf(m, acc2[rt][ct][r] + bb2[ct]);
            m = fmaxf(m, __shfl_xor(m, 16, 64));
            pv[rt][ct] = lrelu(m);
        }
    // ---- pooled x -> LDS tiles ----
    __syncthreads();
    float* xf = (float*)(tb + 4096);            // [16][130]
    char*  tres = tb + 12544;
    if ((lq & 1) == 0) {
        #pragma unroll
        for (int rt = 0; rt < 4; ++rt)
            #pragma unroll
            for (int ct = 0; ct < 2; ++ct) {
                int row = wm * 8 + rt * 2 + (lq >> 1), col = wn * 32 + ct * 16 + lrow;
                *(short*)(tb + swz(row, col * 2)) = f2b(pv[rt][ct]);
                xf[row * 130 + col] = pv[rt][ct];
            }
    }
    __syncthreads();
    // ---- fused res ----
    {
        f32x4 r1 = zv;
        #pragma unroll
        for (int s = 0; s < 4; ++s) {
            bfrag B = ((const bfrag*)rw1p)[(s * 8 + wid) * 64 + lane];
            bfrag a = *(const bfrag*)(tb + swz(lrow, s * 64 + lq * 16));
            r1 = MFMA(a, B, r1);
        }
        float rb1v = rb1[wid * 16 + lrow];
        #pragma unroll
        for (int r = 0; r < 4; ++r) {
            int row = lq * 4 + r;
            *(short*)(tres + swz(row, (wid * 16 + lrow) * 2)) = f2b(lrelu(r1[r] + rb1v));
        }
    }
    __syncthreads();
    {
        f32x4 r2 = zv;
        #pragma unroll
        for (int s = 0; s < 4; ++s) {
            bfrag B = ((const bfrag*)rw2p)[(s * 8 + wid) * 64 + lane];
            bfrag a = *(const bfrag*)(tres + swz(lrow, s * 64 + lq * 16));
            r2 = MFMA(a, B, r2);
        }
        float rb2v = rb2[wid * 16 + lrow];
        int p0 = blockIdx.x * 16;
        #pragma unroll
        for (int r = 0; r < 4; ++r) {
            int row = lq * 4 + r, col = wid * 16 + lrow;
            float v = lrelu(r2[r] + rb2v + xf[row * 130 + col]);
            size_t o = (size_t)(p0 + row) * 128 + col;
            if (out16) out16[o] = f2b(v);
            if (out32) out32[o] = v;
            *(short*)(tb + swz(row, col * 2)) = f2b(v);   // stash for U-GEMM
        }
    }
    __syncthreads();
    // ---- U epilogue: U = out @ W1next[0:128] ----
    if (wu) {
        f32x4 ua = zv;
        #pragma unroll
        for (int s = 0; s < 4; ++s) {
            bfrag B = ((const bfrag*)wu)[(s * 8 + wid) * 64 + lane];
            bfrag a = *(const bfrag*)(tb + swz(lrow, s * 64 + lq * 16));
            ua = MFMA(a, B, ua);
        }
        int p0 = blockIdx.x * 16;
        #pragma unroll
        for (int r = 0; r < 4; ++r)
            Uout[(size_t)(p0 + lq * 4 + r) * 128 + wid * 16 + lrow] = f2b(ua[r]);
    }
}

// ---------------- conv3d 3x3x3 (R9-exact): block M128, 8 waves 2Mx2Nx2K (wave M64xN64xK64) ----------------
__global__ __launch_bounds__(512) void k_conv3(
    const float* __restrict__ gin32, const short* __restrict__ gin16,
    const short* __restrict__ w1p, const float* __restrict__ b1,
    const short* __restrict__ w2p, const float* __restrict__ b2,
    float* __restrict__ gout32, short* __restrict__ gout16) {
    __shared__ __align__(16) char Ab[65536];
    int wid = threadIdx.x >> 6, lane = threadIdx.x & 63, lrow = lane & 15, lq = lane >> 4;
    int kg = wid & 1, wn = (wid >> 1) & 1, wm = wid >> 2;
    int va = blockIdx.x >> 3, vb0 = (blockIdx.x & 7) * 4;
    bfrag zf;
    #pragma unroll
    for (int r = 0; r < 8; ++r) zf[r] = 0;
    f32x4 zv = {0.f, 0.f, 0.f, 0.f};
    f32x4 acc[4][4];
    #pragma unroll
    for (int rt = 0; rt < 4; ++rt)
        #pragma unroll
        for (int ct = 0; ct < 4; ++ct) acc[rt][ct] = zv;
    const bfrag* bp1 = (const bfrag*)w1p;

    #pragma unroll 1
    for (int dai = 0; dai < 3; ++dai) {
        __syncthreads();
        {
            int aa = va + dai - 1;
            bool aok = (unsigned)aa < 32u;
            #pragma unroll
            for (int j = 0; j < 6; ++j) {
                int task = (int)threadIdx.x + j * 512;
                int srow = task >> 4, seg = task & 15;
                int bl = srow >> 5, c = srow & 31;
                int sb = vb0 - 1 + bl;
                bool ok = aok && ((unsigned)sb < 32u);
                size_t gb = ok ? ((size_t)((aa * 32 + sb) * 32 + c) * 128 + seg * 8) : 0;
                bfrag v = *((const bfrag*)gin16 + gb / 8);
                *(bfrag*)(Ab + swz(srow, seg * 16)) = ok ? v : zf;
            }
        }
        __syncthreads();
        #pragma unroll
        for (int t9 = 0; t9 < 9; ++t9) {
            int db = t9 / 3 - 1, dc = t9 % 3 - 1;
            int tap = dai * 9 + t9;
            #pragma unroll
            for (int ss = 0; ss < 2; ++ss) {
                int s = kg * 2 + ss;
                bfrag Bv[4];
                #pragma unroll
                for (int ct = 0; ct < 4; ++ct)
                    Bv[ct] = bp1[((tap * 4 + s) * 8 + wn * 4 + ct) * 64 + lane];
                bfrag av[4];
                #pragma unroll
                for (int rt = 0; rt < 4; ++rt) {
                    int ci = ((rt & 1) << 4) + lrow + dc;
                    bool ok = (unsigned)ci < 32u;
                    int srow2 = (wm * 2 + db + 1 + (rt >> 1)) * 32 + (ok ? ci : 0);
                    bfrag t = *(const bfrag*)(Ab + swz(srow2, s * 64 + lq * 16));
                    av[rt] = ok ? t : zf;
                }
                #pragma unroll
                for (int ct = 0; ct < 4; ++ct)
                    #pragma unroll
                    for (int rt = 0; rt < 4; ++rt) acc[rt][ct] = MFMA(av[rt], Bv[ct], acc[rt][ct]);
            }
        }
    }
    __syncthreads();
    if (kg == 1) {
        int p = wm * 2 + wn;
        #pragma unroll
        for (int rt = 0; rt < 4; ++rt)
            #pragma unroll
            for (int ct = 0; ct < 4; ++ct)
                *(f32x4*)(Ab + p * 16384 + ((rt * 4 + ct) * 64 + lane) * 16) = acc[rt][ct];
    }
    __syncthreads();
    if (kg == 0) {
        int p = wm * 2 + wn;
        #pragma unroll
        for (int rt = 0; rt < 4; ++rt)
            #pragma unroll
            for (int ct = 0; ct < 4; ++ct)
                acc[rt][ct] += *(const f32x4*)(Ab + p * 16384 + ((rt * 4 + ct) * 64 + lane) * 16);
    }
    __syncthreads();
    if (kg == 0) {
        float bb1[4];
        #pragma unroll
        for (int ct = 0; ct < 4; ++ct) bb1[ct] = b1[wn * 64 + ct * 16 + lrow];
        #pragma unroll
        for (int rt = 0; rt < 4; ++rt)
            #pragma unroll
            for (int ct = 0; ct < 4; ++ct)
                #pragma unroll
                for (int r = 0; r < 4; ++r) {
                    int row = wm * 64 + rt * 16 + lq * 4 + r, col = wn * 64 + ct * 16 + lrow;
                    *(short*)(Ab + swz(row, col * 2)) = f2b(lrelu(acc[rt][ct][r] + bb1[ct]));
                }
    }
    __syncthreads();
    int wm2 = wid >> 2, wn2 = wid & 3;
    float bb2[2];
    #pragma unroll
    for (int ct = 0; ct < 2; ++ct) bb2[ct] = b2[wn2 * 32 + ct * 16 + lrow];
    f32x4 acc2[4][2];
    #pragma unroll
    for (int rt = 0; rt < 4; ++rt) { acc2[rt][0] = zv; acc2[rt][1] = zv; }
    const bfrag* bp2 = (const bfrag*)w2p;
    #pragma unroll
    for (int s = 0; s < 4; ++s) {
        bfrag Bv[2];
        #pragma unroll
        for (int ct = 0; ct < 2; ++ct) Bv[ct] = bp2[(s * 8 + wn2 * 2 + ct) * 64 + lane];
        bfrag av[4];
        #pragma unroll
        for (int rt = 0; rt < 4; ++rt) {
            int row = wm2 * 64 + rt * 16 + lrow;
            av[rt] = *(const bfrag*)(Ab + swz(row, s * 64 + lq * 16));
        }
        #pragma unroll
        for (int ct = 0; ct < 2; ++ct)
            #pragma unroll
            for (int rt = 0; rt < 4; ++rt) acc2[rt][ct] = MFMA(av[rt], Bv[ct], acc2[rt][ct]);
    }
    #pragma unroll
    for (int rt = 0; rt < 4; ++rt)
        #pragma unroll
        for (int ct = 0; ct < 2; ++ct)
            #pragma unroll
            for (int r = 0; r < 4; ++r) {
                int row = wm2 * 64 + rt * 16 + lq * 4 + r;
                int voxel = (va * 32 + vb0 + (row >> 5)) * 32 + (row & 31);
                size_t o = (size_t)voxel * 128 + wn2 * 32 + ct * 16 + lrow;
                float v = lrelu(acc2[rt][ct][r] + bb2[ct] + gin32[o]);
                gout32[o] = v; gout16[o] = f2b(v);
            }
}

// ---------------- head: gather + lin1 + lin2 + linb + sigmoid; block M64, 8 waves ----------------
__global__ __launch_bounds__(512) void k_head(
    const short* __restrict__ g16, const int* __restrict__ vx, const int* __restrict__ vmin,
    const short* __restrict__ w1p, const float* __restrict__ b1,
    const short* __restrict__ w2p, const float* __restrict__ b2,
    const float* __restrict__ W3, const float* __restrict__ b3,
    float* __restrict__ out) {
    __shared__ __align__(16) char tb[16384];
    __shared__ float t2[64][129];
    int wid = threadIdx.x >> 6, lane = threadIdx.x & 63, lrow = lane & 15, lq = lane >> 4;
    int rowbase = blockIdx.x * 64;
    int goff[4];
    #pragma unroll
    for (int rt = 0; rt < 4; ++rt) {
        int m = rowbase + rt * 16 + lrow;
        int v0 = vx[m * 3 + 0] - vmin[0];
        int v1 = vx[m * 3 + 1] - vmin[1];
        int v2 = vx[m * 3 + 2] - vmin[2];
        goff[rt] = ((v0 * 32 + v1) * 32 + v2) * 128;
    }
    float bb1 = b1[wid * 16 + lrow], bb2 = b2[wid * 16 + lrow];
    f32x4 zv = {0.f, 0.f, 0.f, 0.f};
    f32x4 acc[4];
    #pragma unroll
    for (int rt = 0; rt < 4; ++rt) acc[rt] = zv;
    const bfrag* bp1 = (const bfrag*)w1p;
    #pragma unroll
    for (int s = 0; s < 4; ++s) {
        bfrag B = bp1[(s * 8 + wid) * 64 + lane];
        #pragma unroll
        for (int rt = 0; rt < 4; ++rt) {
            bfrag a = *((const bfrag*)(g16 + goff[rt]) + s * 4 + lq);
            acc[rt] = MFMA(a, B, acc[rt]);
        }
    }
    #pragma unroll
    for (int rt = 0; rt < 4; ++rt)
        #pragma unroll
        for (int r = 0; r < 4; ++r) {
            int row = rt * 16 + lq * 4 + r, col = wid * 16 + lrow;
            *(short*)(tb + swz(row, col * 2)) = f2b(lrelu(acc[rt][r] + bb1));
        }
    __syncthreads();
    f32x4 acc2[4];
    #pragma unroll
    for (int rt = 0; rt < 4; ++rt) acc2[rt] = zv;
    const bfrag* bp2 = (const bfrag*)w2p;
    #pragma unroll
    for (int s = 0; s < 4; ++s) {
        bfrag B = bp2[(s * 8 + wid) * 64 + lane];
        #pragma unroll
        for (int rt = 0; rt < 4; ++rt) {
            int row = rt * 16 + lrow;
            bfrag av = *(const bfrag*)(tb + swz(row, s * 64 + lq * 16));
            acc2[rt] = MFMA(av, B, acc2[rt]);
        }
    }
    #pragma unroll
    for (int rt = 0; rt < 4; ++rt)
        #pragma unroll
        for (int r = 0; r < 4; ++r) {
            int row = rt * 16 + lq * 4 + r, col = wid * 16 + lrow;
            t2[row][col] = lrelu(acc2[rt][r] + bb2);
        }
    __syncthreads();
    if (threadIdx.x < 192) {
        int row = threadIdx.x & 63, c = threadIdx.x >> 6;
        float s = b3[c];
        #pragma unroll 4
        for (int k = 0; k < 128; ++k) s += t2[row][k] * W3[k * 3 + c];
        out[(size_t)(rowbase + row) * 3 + c] = 1.f / (1.f + expf(-s));
    }
}

// ---------------- small kernels ----------------
__global__ void k_vmin(const int* __restrict__ vx, int M, int* __restrict__ vmin) {
    __shared__ int sm[3 * 256];
    int t = threadIdx.x;
    int m0 = 0x7fffffff, m1 = 0x7fffffff, m2 = 0x7fffffff;
    for (int i = t; i < M; i += 256) {
        m0 = min(m0, vx[i * 3 + 0]); m1 = min(m1, vx[i * 3 + 1]); m2 = min(m2, vx[i * 3 + 2]);
    }
    sm[t] = m0; sm[256 + t] = m1; sm[512 + t] = m2;
    __syncthreads();
    for (int s = 128; s > 0; s >>= 1) {
        if (t < s) {
            sm[t] = min(sm[t], sm[t + s]);
            sm[256 + t] = min(sm[256 + t], sm[256 + t + s]);
            sm[512 + t] = min(sm[512 + t], sm[512 + t + s]);
        }
        __syncthreads();
    }
    if (t == 0) { vmin[0] = sm[0]; vmin[1] = sm[256]; vmin[2] = sm[512]; }
}

__global__ void k_scatter(const float* __restrict__ vf, const int* __restrict__ vx,
                          const int* __restrict__ vmin, float* __restrict__ g32, short* __restrict__ g16) {
    int m = blockIdx.x, j = threadIdx.x;
    int v0 = vx[m * 3 + 0] - vmin[0];
    int v1 = vx[m * 3 + 1] - vmin[1];
    int v2 = vx[m * 3 + 2] - vmin[2];
    size_t o = (size_t)(((v0 * GDIM) + v1) * GDIM + v2) * EF + j;
    float v = vf[(size_t)m * EF + j];
    g32[o] = v; g16[o] = f2b(v);
}

extern "C" void kernel_launch(void* const* d_in, const int* in_sizes, int n_in,
                              void* d_out, int out_size, void* d_ws, size_t ws_size,
                              hipStream_t stream) {
    const int*   pc_idx  = (const int*)  d_in[0];
    const float* pc_xyz  = (const float*)d_in[1];
    const int*   vox_int = (const int*)  d_in[2];
    const int*   vox_idx = (const int*)  d_in[3];
    const float* vox_xyz = (const float*)d_in[4];
    const float* pcf_W1  = (const float*)d_in[5];
    const float* pcf_b1  = (const float*)d_in[6];
    const float* pcf_W2  = (const float*)d_in[7];
    const float* pcf_b2  = (const float*)d_in[8];
    const float* pcres_W1 = (const float*)d_in[9];
    const float* pcres_b1 = (const float*)d_in[10];
    const float* pcres_W2 = (const float*)d_in[11];
    const float* pcres_b2 = (const float*)d_in[12];
    const float* pcc_W1  = (const float*)d_in[13];
    const float* pcc_b1  = (const float*)d_in[14];
    const float* pcc_W2  = (const float*)d_in[15];
    const float* pcc_b2  = (const float*)d_in[16];
    const float* r3_Wc1  = (const float*)d_in[17];
    const float* r3_bc1  = (const float*)d_in[18];
    const float* r3_Wc2  = (const float*)d_in[19];
    const float* r3_bc2  = (const float*)d_in[20];
    const float* lin1_W  = (const float*)d_in[21];
    const float* lin1_b  = (const float*)d_in[22];
    const float* lin2_W  = (const float*)d_in[23];
    const float* lin2_b  = (const float*)d_in[24];
    const float* linb_W  = (const float*)d_in[25];
    const float* linb_b  = (const float*)d_in[26];

    const size_t NE = (size_t)NPTS * EF;   // 4M elements
    float* A32 = (float*)d_ws;
    float* B32 = A32 + NE;
    short* A16 = (short*)(B32 + NE);       // doubles as U ping buffer
    short* B16 = A16 + NE;                 // doubles as U pong buffer
    float* Y32 = (float*)(B16 + NE);
    short* Y16 = (short*)(Y32 + NE);
    short* pcf_w1p = Y16 + NE;                 // 1 step
    short* pcf_w2p = pcf_w1p + 1 * 4096;
    short* pcc_w1p = pcf_w2p + 4 * 4096;       // 6 layers x 5 steps
    short* pcc_w2p = pcc_w1p + 6 * 5 * 4096;   // 6 x 4
    short* pcr_w1p = pcc_w2p + 6 * 4 * 4096;   // 7 x 4
    short* pcr_w2p = pcr_w1p + 7 * 4 * 4096;
    short* wc2p    = pcr_w2p + 7 * 4 * 4096;   // 8 x 4
    short* lin1p   = wc2p    + 8 * 4 * 4096;
    short* lin2p   = lin1p   + 4 * 4096;
    short* wc1p    = lin2p   + 4 * 4096;       // 8 layers x 108 steps (pre-packed upfront)
    int*   vmin    = (int*)(wc1p + 8 * 108 * 4096);

    // ---- pack ALL weights upfront (batched: 10 launches total) ----
    k_pack_w<<<16, 256, 0, stream>>>(pcf_W1, pcf_w1p, 3, 1, 128, 1, 0, 0, 1);
    k_pack_w<<<64, 256, 0, stream>>>(pcf_W2, pcf_w2p, 128, 4, 128, 1, 0, 0, 1);
    k_pack_w<<<480, 256, 0, stream>>>(pcc_W1, pcc_w1p, 131, 5, 128, 1, 131 * 128, 5 * 4096, 6);
    k_pack_w<<<384, 256, 0, stream>>>(pcc_W2, pcc_w2p, 128, 4, 128, 1, 128 * 128, 4 * 4096, 6);
    k_pack_w<<<448, 256, 0, stream>>>(pcres_W1, pcr_w1p, 128, 4, 128, 1, 128 * 128, 4 * 4096, 7);
    k_pack_w<<<448, 256, 0, stream>>>(pcres_W2, pcr_w2p, 128, 4, 128, 1, 128 * 128, 4 * 4096, 7);
    k_pack_w<<<512, 256, 0, stream>>>(r3_Wc2, wc2p, 128, 4, 1, 128, 128 * 128, 4 * 4096, 8);
    k_pack_w<<<64, 256, 0, stream>>>(lin1_W, lin1p, 128, 4, 128, 1, 0, 0, 1);
    k_pack_w<<<64, 256, 0, stream>>>(lin2_W, lin2p, 128, 4, 128, 1, 0, 0, 1);
    k_pack_wc1<<<8 * 1728, 256, 0, stream>>>(r3_Wc1, wc1p);

    // ---- point-cloud stack: U-factored gather (GEMM1 on unique rows, fused into prior epilogue) ----
    short* UA = A16; short* UB = B16;
    k_pcfirst<<<NPTS * KNN / 128, 512, 0, stream>>>(pc_xyz, pcf_w1p, pcf_b1, pcf_w2p, pcf_b2,
        pcr_w1p, pcres_b1, pcr_w2p, pcres_b2,
        pcc_w1p /* U0 = out0 @ W1[layer0][0:128] */, UA, nullptr, nullptr);
    short* curU = UA; short* nxtU = UB;
    for (int i = 0; i < 5; ++i) {
        k_pcconv<<<NPTS * KNN / 128, 512, 0, stream>>>(curU, pc_idx, pc_xyz,
            pcc_W1 + (size_t)i * 131 * 128, pcc_b1 + i * EF,
            pcc_w2p + (size_t)i * 4 * 4096, pcc_b2 + i * EF,
            pcr_w1p + (size_t)(i + 1) * 4 * 4096, pcres_b1 + (i + 1) * EF,
            pcr_w2p + (size_t)(i + 1) * 4 * 4096, pcres_b2 + (i + 1) * EF,
            pcc_w1p + (size_t)(i + 1) * 5 * 4096, nxtU, nullptr, nullptr);
        short* t = curU; curU = nxtU; nxtU = t;
    }
    // voxel layer: no U-next; writes fp32+bf16 voxel feats (A32 / A16 region is dead for U)
    k_pcconv<<<MVOX * KNN / 128, 512, 0, stream>>>(curU, vox_idx, vox_xyz,
        pcc_W1 + (size_t)5 * 131 * 128, pcc_b1 + 5 * EF,
        pcc_w2p + (size_t)5 * 4 * 4096, pcc_b2 + 5 * EF,
        pcr_w1p + (size_t)6 * 4 * 4096, pcres_b1 + 6 * EF,
        pcr_w2p + (size_t)6 * 4 * 4096, pcres_b2 + 6 * EF,
        nullptr, nullptr, A32, A16);

    k_vmin<<<1, 256, 0, stream>>>(vox_int, MVOX, vmin);
    hipMemsetAsync(B32, 0, NE * sizeof(float), stream);
    hipMemsetAsync(B16, 0, NE * sizeof(short), stream);
    k_scatter<<<MVOX, 128, 0, stream>>>(A32, vox_int, vmin, B32, B16);

    // ---- 8 x resnet_block_rec3 (ping-pong B <-> Y), weights pre-packed ----
    float* cur32 = B32; short* curg = B16;
    float* nxt32 = Y32; short* nxtg = Y16;
    for (int i = 0; i < 8; ++i) {
        k_conv3<<<256, 512, 0, stream>>>(cur32, curg, wc1p + (size_t)i * 108 * 4096, r3_bc1 + i * EF,
                                         wc2p + (size_t)i * 4 * 4096, r3_bc2 + i * EF,
                                         nxt32, nxtg);
        float* t32 = cur32; cur32 = nxt32; nxt32 = t32;
        short* t16 = curg; curg = nxtg; nxtg = t16;
    }

    // ---- head ----
    k_head<<<MVOX / 64, 512, 0, stream>>>(curg, vox_int, vmin,
                                          lin1p, lin1_b, lin2p, lin2_b, linb_W, linb_b,
                                          (float*)d_out);
}

// Round 14
// 648.136 us; speedup vs baseline: 1.2775x; 1.2775x over previous
//
#include <hip/hip_runtime.h>
#include <math.h>

#define EF 128
#define NPTS 32768
#define KNN 8
#define MVOX 8192
#define GDIM 32
#define NVOXG (GDIM*GDIM*GDIM)

typedef __attribute__((ext_vector_type(8))) short bfrag;   // 8 x bf16
typedef __attribute__((ext_vector_type(4))) float f32x4;

__device__ __forceinline__ float lrelu(float x) { return x > 0.f ? x : 0.01f * x; }
__device__ __forceinline__ short f2b(float f) {            // fp32 -> bf16 (RNE)
    unsigned u = __float_as_uint(f);
    return (short)((u + 0x7fff + ((u >> 16) & 1)) >> 16);
}
#define MFMA(a,b,c) __builtin_amdgcn_mfma_f32_16x16x32_bf16((a),(b),(c),0,0,0)
// LDS tile addressing: row-major 256B rows, XOR swizzle on byte bits 4-6
__device__ __forceinline__ int swz(int row, int bytecol) {
    return row * 256 + (bytecol ^ ((row & 7) << 4));
}

// ------- batched weight packing: n_layers x [W[k][col] -> [step][ct][lane][8] bf16] -------
__global__ void k_pack_w(const float* __restrict__ src, short* __restrict__ dst,
                         int K_real, int n_steps, int k_str, int c_str,
                         int src_ls, int dst_ls, int n_layers) {
    int t = blockIdx.x * 256 + threadIdx.x;
    int per = n_steps * 4096;
    if (t >= n_layers * per) return;
    int layer = t / per;
    int u = t - layer * per;
    int r = u & 7, l = (u >> 3) & 63, ct = (u >> 9) & 7, s = u >> 12;
    int k = s * 32 + (l >> 4) * 8 + r;
    int col = ct * 16 + (l & 15);
    float v = (k < K_real) ? src[(size_t)layer * src_ls + (size_t)k * k_str + (size_t)col * c_str] : 0.f;
    dst[(size_t)layer * dst_ls + u] = f2b(v);
}
// conv3x3x3 weights, 8 layers: [o][ci][27] -> [tap*4+cc][ct][lane][8]
__global__ void k_pack_wc1(const float* __restrict__ src, short* __restrict__ dst) {
    int g = blockIdx.x;
    int layer = g / 1728;
    int t = (g - layer * 1728) * 256 + threadIdx.x;
    if (t >= 108 * 4096) return;
    int r = t & 7, l = (t >> 3) & 63, ct = (t >> 9) & 7, s = t >> 12;
    int tap = s >> 2;
    int ci = (s & 3) * 32 + (l >> 4) * 8 + r;
    int col = ct * 16 + (l & 15);
    dst[(size_t)layer * 442368 + t] =
        f2b(src[(size_t)layer * 442368 + ((size_t)col * 128 + ci) * 27 + tap]);
}

// ============ template: block = 128 gather-rows (16 out rows), 8 waves 2Mx4N, fused res ============

// ---------------- pc_conv_first: MFMA phase-1 + GEMM2 + pool + fused res0 ----------------
__global__ __launch_bounds__(512) void k_pcfirst(
    const float* __restrict__ xyz, const short* __restrict__ w1p, const float* __restrict__ b1,
    const short* __restrict__ w2p, const float* __restrict__ b2,
    const short* __restrict__ rw1p, const float* __restrict__ rb1,
    const short* __restrict__ rw2p, const float* __restrict__ rb2,
    float* __restrict__ out32, short* __restrict__ out16) {
    __shared__ __align__(16) char tb[32768];
    int wid = threadIdx.x >> 6, lane = threadIdx.x & 63, lrow = lane & 15, lq = lane >> 4;
    int wm = wid >> 2, wn = wid & 3;
    int rowbase = blockIdx.x * 128;
    f32x4 zv = {0.f, 0.f, 0.f, 0.f};
    // ---- phase 1: 3->128 via 1-k-step MFMA ----
    {
        f32x4 acc1[4][2];
        #pragma unroll
        for (int rt = 0; rt < 4; ++rt) { acc1[rt][0] = zv; acc1[rt][1] = zv; }
        bfrag Bv[2];
        #pragma unroll
        for (int ct = 0; ct < 2; ++ct) Bv[ct] = ((const bfrag*)w1p)[(wn * 2 + ct) * 64 + lane];
        #pragma unroll
        for (int rt = 0; rt < 4; ++rt) {
            bfrag a4;
            #pragma unroll
            for (int r = 0; r < 8; ++r) a4[r] = 0;
            if (lq == 0) {
                int gr = rowbase + wm * 64 + rt * 16 + lrow;
                a4[0] = f2b(xyz[gr * 3]); a4[1] = f2b(xyz[gr * 3 + 1]); a4[2] = f2b(xyz[gr * 3 + 2]);
            }
            #pragma unroll
            for (int ct = 0; ct < 2; ++ct) acc1[rt][ct] = MFMA(a4, Bv[ct], acc1[rt][ct]);
        }
        float bb1[2];
        #pragma unroll
        for (int ct = 0; ct < 2; ++ct) bb1[ct] = b1[wn * 32 + ct * 16 + lrow];
        #pragma unroll
        for (int rt = 0; rt < 4; ++rt)
            #pragma unroll
            for (int ct = 0; ct < 2; ++ct)
                #pragma unroll
                for (int r = 0; r < 4; ++r) {
                    int row = wm * 64 + rt * 16 + lq * 4 + r, col = wn * 32 + ct * 16 + lrow;
                    *(short*)(tb + swz(row, col * 2)) = f2b(lrelu(acc1[rt][ct][r] + bb1[ct]));
                }
    }
    __syncthreads();
    // ---- GEMM2 + pool ----
    float bb2[2];
    #pragma unroll
    for (int ct = 0; ct < 2; ++ct) bb2[ct] = b2[wn * 32 + ct * 16 + lrow];
    f32x4 acc[4][2];
    #pragma unroll
    for (int rt = 0; rt < 4; ++rt) { acc[rt][0] = zv; acc[rt][1] = zv; }
    const bfrag* bp2 = (const bfrag*)w2p;
    #pragma unroll
    for (int s = 0; s < 4; ++s) {
        bfrag Bv[2];
        #pragma unroll
        for (int ct = 0; ct < 2; ++ct) Bv[ct] = bp2[(s * 8 + wn * 2 + ct) * 64 + lane];
        bfrag av[4];
        #pragma unroll
        for (int rt = 0; rt < 4; ++rt) {
            int row = wm * 64 + rt * 16 + lrow;
            av[rt] = *(const bfrag*)(tb + swz(row, s * 64 + lq * 16));
        }
        #pragma unroll
        for (int ct = 0; ct < 2; ++ct)
            #pragma unroll
            for (int rt = 0; rt < 4; ++rt) acc[rt][ct] = MFMA(av[rt], Bv[ct], acc[rt][ct]);
    }
    float pv[4][2];
    #pragma unroll
    for (int rt = 0; rt < 4; ++rt)
        #pragma unroll
        for (int ct = 0; ct < 2; ++ct) {
            float m = -INFINITY;
            #pragma unroll
            for (int r = 0; r < 4; ++r) m = fmaxf(m, acc[rt][ct][r] + bb2[ct]);
            m = fmaxf(m, __shfl_xor(m, 16, 64));
            pv[rt][ct] = lrelu(m);
        }
    // ---- pooled x -> LDS tiles ----
    __syncthreads();
    float* xf = (float*)(tb + 4096);            // [16][130]
    char*  tres = tb + 12544;                   // 16-row swizzled bf16 tile
    if ((lq & 1) == 0) {
        #pragma unroll
        for (int rt = 0; rt < 4; ++rt)
            #pragma unroll
            for (int ct = 0; ct < 2; ++ct) {
                int row = wm * 8 + rt * 2 + (lq >> 1), col = wn * 32 + ct * 16 + lrow;
                *(short*)(tb + swz(row, col * 2)) = f2b(pv[rt][ct]);
                xf[row * 130 + col] = pv[rt][ct];
            }
    }
    __syncthreads();
    // ---- fused res: GEMM1 ----
    {
        f32x4 r1 = zv;
        #pragma unroll
        for (int s = 0; s < 4; ++s) {
            bfrag B = ((const bfrag*)rw1p)[(s * 8 + wid) * 64 + lane];
            bfrag a = *(const bfrag*)(tb + swz(lrow, s * 64 + lq * 16));
            r1 = MFMA(a, B, r1);
        }
        float rb1v = rb1[wid * 16 + lrow];
        #pragma unroll
        for (int r = 0; r < 4; ++r) {
            int row = lq * 4 + r;
            *(short*)(tres + swz(row, (wid * 16 + lrow) * 2)) = f2b(lrelu(r1[r] + rb1v));
        }
    }
    __syncthreads();
    {
        f32x4 r2 = zv;
        #pragma unroll
        for (int s = 0; s < 4; ++s) {
            bfrag B = ((const bfrag*)rw2p)[(s * 8 + wid) * 64 + lane];
            bfrag a = *(const bfrag*)(tres + swz(lrow, s * 64 + lq * 16));
            r2 = MFMA(a, B, r2);
        }
        float rb2v = rb2[wid * 16 + lrow];
        int p0 = blockIdx.x * 16;
        #pragma unroll
        for (int r = 0; r < 4; ++r) {
            int row = lq * 4 + r, col = wid * 16 + lrow;
            float v = lrelu(r2[r] + rb2v + xf[row * 130 + col]);
            size_t o = (size_t)(p0 + row) * 128 + col;
            out16[o] = f2b(v);
            if (out32) out32[o] = v;
        }
    }
}

// ---------------- pc_conv: staged gather + 131->128 + 128->128 + pool + fused res ----------------
__global__ __launch_bounds__(512) void k_pcconv(
    const short* __restrict__ fin16, const int* __restrict__ idx, const float* __restrict__ xyz,
    const short* __restrict__ w1p, const float* __restrict__ b1,
    const short* __restrict__ w2p, const float* __restrict__ b2,
    const short* __restrict__ rw1p, const float* __restrict__ rb1,
    const short* __restrict__ rw2p, const float* __restrict__ rb2,
    float* __restrict__ out32, short* __restrict__ out16) {
    __shared__ __align__(16) char tb[32768];
    int wid = threadIdx.x >> 6, lane = threadIdx.x & 63, lrow = lane & 15, lq = lane >> 4;
    int wm = wid >> 2, wn = wid & 3;
    int rowbase = blockIdx.x * 128;
    f32x4 zv = {0.f, 0.f, 0.f, 0.f};
    // stage gathered rows once per block
    {
        int srow = threadIdx.x >> 2, sseg = threadIdx.x & 3;
        int nb = idx[rowbase + srow];
        const bfrag* src = (const bfrag*)(fin16 + (size_t)nb * 128);
        #pragma unroll
        for (int j = 0; j < 4; ++j) {
            int seg = sseg + j * 4;
            bfrag v = src[seg];
            *(bfrag*)(tb + swz(srow, seg * 16)) = v;
        }
    }
    __syncthreads();
    float bb1[2], bb2[2];
    #pragma unroll
    for (int ct = 0; ct < 2; ++ct) {
        bb1[ct] = b1[wn * 32 + ct * 16 + lrow];
        bb2[ct] = b2[wn * 32 + ct * 16 + lrow];
    }
    f32x4 acc[4][2];
    #pragma unroll
    for (int rt = 0; rt < 4; ++rt) { acc[rt][0] = zv; acc[rt][1] = zv; }
    const bfrag* bp1 = (const bfrag*)w1p;
    #pragma unroll
    for (int s = 0; s < 4; ++s) {
        bfrag Bv[2];
        #pragma unroll
        for (int ct = 0; ct < 2; ++ct) Bv[ct] = bp1[(s * 8 + wn * 2 + ct) * 64 + lane];
        bfrag av[4];
        #pragma unroll
        for (int rt = 0; rt < 4; ++rt) {
            int row = wm * 64 + rt * 16 + lrow;
            av[rt] = *(const bfrag*)(tb + swz(row, s * 64 + lq * 16));
        }
        #pragma unroll
        for (int ct = 0; ct < 2; ++ct)
            #pragma unroll
            for (int rt = 0; rt < 4; ++rt) acc[rt][ct] = MFMA(av[rt], Bv[ct], acc[rt][ct]);
    }
    {   // k-step 4: xyz concat (cols 128..130)
        bfrag Bv[2];
        #pragma unroll
        for (int ct = 0; ct < 2; ++ct) Bv[ct] = bp1[(32 + wn * 2 + ct) * 64 + lane];
        #pragma unroll
        for (int rt = 0; rt < 4; ++rt) {
            bfrag a4;
            #pragma unroll
            for (int r = 0; r < 8; ++r) a4[r] = 0;
            if (lq == 0) {
                int gr = rowbase + wm * 64 + rt * 16 + lrow;
                a4[0] = f2b(xyz[gr * 3]); a4[1] = f2b(xyz[gr * 3 + 1]); a4[2] = f2b(xyz[gr * 3 + 2]);
            }
            #pragma unroll
            for (int ct = 0; ct < 2; ++ct) acc[rt][ct] = MFMA(a4, Bv[ct], acc[rt][ct]);
        }
    }
    __syncthreads();   // all GEMM1 reads of tb done before overwrite
    #pragma unroll
    for (int rt = 0; rt < 4; ++rt)
        #pragma unroll
        for (int ct = 0; ct < 2; ++ct)
            #pragma unroll
            for (int r = 0; r < 4; ++r) {
                int row = wm * 64 + rt * 16 + lq * 4 + r, col = wn * 32 + ct * 16 + lrow;
                *(short*)(tb + swz(row, col * 2)) = f2b(lrelu(acc[rt][ct][r] + bb1[ct]));
            }
    __syncthreads();
    f32x4 acc2[4][2];
    #pragma unroll
    for (int rt = 0; rt < 4; ++rt) { acc2[rt][0] = zv; acc2[rt][1] = zv; }
    const bfrag* bp2 = (const bfrag*)w2p;
    #pragma unroll
    for (int s = 0; s < 4; ++s) {
        bfrag Bv[2];
        #pragma unroll
        for (int ct = 0; ct < 2; ++ct) Bv[ct] = bp2[(s * 8 + wn * 2 + ct) * 64 + lane];
        bfrag av[4];
        #pragma unroll
        for (int rt = 0; rt < 4; ++rt) {
            int row = wm * 64 + rt * 16 + lrow;
            av[rt] = *(const bfrag*)(tb + swz(row, s * 64 + lq * 16));
        }
        #pragma unroll
        for (int ct = 0; ct < 2; ++ct)
            #pragma unroll
            for (int rt = 0; rt < 4; ++rt) acc2[rt][ct] = MFMA(av[rt], Bv[ct], acc2[rt][ct]);
    }
    float pv[4][2];
    #pragma unroll
    for (int rt = 0; rt < 4; ++rt)
        #pragma unroll
        for (int ct = 0; ct < 2; ++ct) {
            float m = -INFINITY;
            #pragma unroll
            for (int r = 0; r < 4; ++r) m = fmaxf(m, acc2[rt][ct][r] + bb2[ct]);
            m = fmaxf(m, __shfl_xor(m, 16, 64));
            pv[rt][ct] = lrelu(m);
        }
    // ---- pooled x -> LDS tiles ----
    __syncthreads();
    float* xf = (float*)(tb + 4096);            // [16][130]
    char*  tres = tb + 12544;
    if ((lq & 1) == 0) {
        #pragma unroll
        for (int rt = 0; rt < 4; ++rt)
            #pragma unroll
            for (int ct = 0; ct < 2; ++ct) {
                int row = wm * 8 + rt * 2 + (lq >> 1), col = wn * 32 + ct * 16 + lrow;
                *(short*)(tb + swz(row, col * 2)) = f2b(pv[rt][ct]);
                xf[row * 130 + col] = pv[rt][ct];
            }
    }
    __syncthreads();
    // ---- fused res ----
    {
        f32x4 r1 = zv;
        #pragma unroll
        for (int s = 0; s < 4; ++s) {
            bfrag B = ((const bfrag*)rw1p)[(s * 8 + wid) * 64 + lane];
            bfrag a = *(const bfrag*)(tb + swz(lrow, s * 64 + lq * 16));
            r1 = MFMA(a, B, r1);
        }
        float rb1v = rb1[wid * 16 + lrow];
        #pragma unroll
        for (int r = 0; r < 4; ++r) {
            int row = lq * 4 + r;
            *(short*)(tres + swz(row, (wid * 16 + lrow) * 2)) = f2b(lrelu(r1[r] + rb1v));
        }
    }
    __syncthreads();
    {
        f32x4 r2 = zv;
        #pragma unroll
        for (int s = 0; s < 4; ++s) {
            bfrag B = ((const bfrag*)rw2p)[(s * 8 + wid) * 64 + lane];
            bfrag a = *(const bfrag*)(tres + swz(lrow, s * 64 + lq * 16));
            r2 = MFMA(a, B, r2);
        }
        float rb2v = rb2[wid * 16 + lrow];
        int p0 = blockIdx.x * 16;
        #pragma unroll
        for (int r = 0; r < 4; ++r) {
            int row = lq * 4 + r, col = wid * 16 + lrow;
            float v = lrelu(r2[r] + rb2v + xf[row * 130 + col]);
            size_t o = (size_t)(p0 + row) * 128 + col;
            out16[o] = f2b(v);
            if (out32) out32[o] = v;
        }
    }
}

// ---------------- conv3d 3x3x3 (R9-exact): block M128, 8 waves 2Mx2Nx2K (wave M64xN64xK64) ----------------
// single-buffered 48KB slab per da; k-reduce between wave pairs; fused 1x1 + residual
__global__ __launch_bounds__(512) void k_conv3(
    const float* __restrict__ gin32, const short* __restrict__ gin16,
    const short* __restrict__ w1p, const float* __restrict__ b1,
    const short* __restrict__ w2p, const float* __restrict__ b2,
    float* __restrict__ gout32, short* __restrict__ gout16) {
    __shared__ __align__(16) char Ab[65536];
    int wid = threadIdx.x >> 6, lane = threadIdx.x & 63, lrow = lane & 15, lq = lane >> 4;
    int kg = wid & 1, wn = (wid >> 1) & 1, wm = wid >> 2;
    int va = blockIdx.x >> 3, vb0 = (blockIdx.x & 7) * 4;
    bfrag zf;
    #pragma unroll
    for (int r = 0; r < 8; ++r) zf[r] = 0;
    f32x4 zv = {0.f, 0.f, 0.f, 0.f};
    f32x4 acc[4][4];
    #pragma unroll
    for (int rt = 0; rt < 4; ++rt)
        #pragma unroll
        for (int ct = 0; ct < 4; ++ct) acc[rt][ct] = zv;
    const bfrag* bp1 = (const bfrag*)w1p;

    #pragma unroll 1
    for (int dai = 0; dai < 3; ++dai) {
        __syncthreads();
        {
            int aa = va + dai - 1;
            bool aok = (unsigned)aa < 32u;
            #pragma unroll
            for (int j = 0; j < 6; ++j) {
                int task = (int)threadIdx.x + j * 512;
                int srow = task >> 4, seg = task & 15;
                int bl = srow >> 5, c = srow & 31;
                int sb = vb0 - 1 + bl;
                bool ok = aok && ((unsigned)sb < 32u);
                size_t gb = ok ? ((size_t)((aa * 32 + sb) * 32 + c) * 128 + seg * 8) : 0;
                bfrag v = *((const bfrag*)gin16 + gb / 8);
                *(bfrag*)(Ab + swz(srow, seg * 16)) = ok ? v : zf;
            }
        }
        __syncthreads();
        #pragma unroll
        for (int t9 = 0; t9 < 9; ++t9) {
            int db = t9 / 3 - 1, dc = t9 % 3 - 1;
            int tap = dai * 9 + t9;
            #pragma unroll
            for (int ss = 0; ss < 2; ++ss) {
                int s = kg * 2 + ss;
                bfrag Bv[4];
                #pragma unroll
                for (int ct = 0; ct < 4; ++ct)
                    Bv[ct] = bp1[((tap * 4 + s) * 8 + wn * 4 + ct) * 64 + lane];
                bfrag av[4];
                #pragma unroll
                for (int rt = 0; rt < 4; ++rt) {
                    int ci = ((rt & 1) << 4) + lrow + dc;
                    bool ok = (unsigned)ci < 32u;
                    int srow2 = (wm * 2 + db + 1 + (rt >> 1)) * 32 + (ok ? ci : 0);
                    bfrag t = *(const bfrag*)(Ab + swz(srow2, s * 64 + lq * 16));
                    av[rt] = ok ? t : zf;
                }
                #pragma unroll
                for (int ct = 0; ct < 4; ++ct)
                    #pragma unroll
                    for (int rt = 0; rt < 4; ++rt) acc[rt][ct] = MFMA(av[rt], Bv[ct], acc[rt][ct]);
            }
        }
    }
    __syncthreads();
    if (kg == 1) {
        int p = wm * 2 + wn;
        #pragma unroll
        for (int rt = 0; rt < 4; ++rt)
            #pragma unroll
            for (int ct = 0; ct < 4; ++ct)
                *(f32x4*)(Ab + p * 16384 + ((rt * 4 + ct) * 64 + lane) * 16) = acc[rt][ct];
    }
    __syncthreads();
    if (kg == 0) {
        int p = wm * 2 + wn;
        #pragma unroll
        for (int rt = 0; rt < 4; ++rt)
            #pragma unroll
            for (int ct = 0; ct < 4; ++ct)
                acc[rt][ct] += *(const f32x4*)(Ab + p * 16384 + ((rt * 4 + ct) * 64 + lane) * 16);
    }
    __syncthreads();
    if (kg == 0) {
        float bb1[4];
        #pragma unroll
        for (int ct = 0; ct < 4; ++ct) bb1[ct] = b1[wn * 64 + ct * 16 + lrow];
        #pragma unroll
        for (int rt = 0; rt < 4; ++rt)
            #pragma unroll
            for (int ct = 0; ct < 4; ++ct)
                #pragma unroll
                for (int r = 0; r < 4; ++r) {
                    int row = wm * 64 + rt * 16 + lq * 4 + r, col = wn * 64 + ct * 16 + lrow;
                    *(short*)(Ab + swz(row, col * 2)) = f2b(lrelu(acc[rt][ct][r] + bb1[ct]));
                }
    }
    __syncthreads();
    int wm2 = wid >> 2, wn2 = wid & 3;
    float bb2[2];
    #pragma unroll
    for (int ct = 0; ct < 2; ++ct) bb2[ct] = b2[wn2 * 32 + ct * 16 + lrow];
    f32x4 acc2[4][2];
    #pragma unroll
    for (int rt = 0; rt < 4; ++rt) { acc2[rt][0] = zv; acc2[rt][1] = zv; }
    const bfrag* bp2 = (const bfrag*)w2p;
    #pragma unroll
    for (int s = 0; s < 4; ++s) {
        bfrag Bv[2];
        #pragma unroll
        for (int ct = 0; ct < 2; ++ct) Bv[ct] = bp2[(s * 8 + wn2 * 2 + ct) * 64 + lane];
        bfrag av[4];
        #pragma unroll
        for (int rt = 0; rt < 4; ++rt) {
            int row = wm2 * 64 + rt * 16 + lrow;
            av[rt] = *(const bfrag*)(Ab + swz(row, s * 64 + lq * 16));
        }
        #pragma unroll
        for (int ct = 0; ct < 2; ++ct)
            #pragma unroll
            for (int rt = 0; rt < 4; ++rt) acc2[rt][ct] = MFMA(av[rt], Bv[ct], acc2[rt][ct]);
    }
    #pragma unroll
    for (int rt = 0; rt < 4; ++rt)
        #pragma unroll
        for (int ct = 0; ct < 2; ++ct)
            #pragma unroll
            for (int r = 0; r < 4; ++r) {
                int row = wm2 * 64 + rt * 16 + lq * 4 + r;
                int voxel = (va * 32 + vb0 + (row >> 5)) * 32 + (row & 31);
                size_t o = (size_t)voxel * 128 + wn2 * 32 + ct * 16 + lrow;
                float v = lrelu(acc2[rt][ct][r] + bb2[ct] + gin32[o]);
                gout32[o] = v; gout16[o] = f2b(v);
            }
}

// ---------------- head: gather + lin1 + lin2 + linb + sigmoid; block M64, 8 waves ----------------
__global__ __launch_bounds__(512) void k_head(
    const short* __restrict__ g16, const int* __restrict__ vx, const int* __restrict__ vmin,
    const short* __restrict__ w1p, const float* __restrict__ b1,
    const short* __restrict__ w2p, const float* __restrict__ b2,
    const float* __restrict__ W3, const float* __restrict__ b3,
    float* __restrict__ out) {
    __shared__ __align__(16) char tb[16384];
    __shared__ float t2[64][129];
    int wid = threadIdx.x >> 6, lane = threadIdx.x & 63, lrow = lane & 15, lq = lane >> 4;
    int rowbase = blockIdx.x * 64;
    int goff[4];
    #pragma unroll
    for (int rt = 0; rt < 4; ++rt) {
        int m = rowbase + rt * 16 + lrow;
        int v0 = vx[m * 3 + 0] - vmin[0];
        int v1 = vx[m * 3 + 1] - vmin[1];
        int v2 = vx[m * 3 + 2] - vmin[2];
        goff[rt] = ((v0 * 32 + v1) * 32 + v2) * 128;
    }
    float bb1 = b1[wid * 16 + lrow], bb2 = b2[wid * 16 + lrow];
    f32x4 zv = {0.f, 0.f, 0.f, 0.f};
    f32x4 acc[4];
    #pragma unroll
    for (int rt = 0; rt < 4; ++rt) acc[rt] = zv;
    const bfrag* bp1 = (const bfrag*)w1p;
    #pragma unroll
    for (int s = 0; s < 4; ++s) {
        bfrag B = bp1[(s * 8 + wid) * 64 + lane];
        #pragma unroll
        for (int rt = 0; rt < 4; ++rt) {
            bfrag a = *((const bfrag*)(g16 + goff[rt]) + s * 4 + lq);
            acc[rt] = MFMA(a, B, acc[rt]);
        }
    }
    #pragma unroll
    for (int rt = 0; rt < 4; ++rt)
        #pragma unroll
        for (int r = 0; r < 4; ++r) {
            int row = rt * 16 + lq * 4 + r, col = wid * 16 + lrow;
            *(short*)(tb + swz(row, col * 2)) = f2b(lrelu(acc[rt][r] + bb1));
        }
    __syncthreads();
    f32x4 acc2[4];
    #pragma unroll
    for (int rt = 0; rt < 4; ++rt) acc2[rt] = zv;
    const bfrag* bp2 = (const bfrag*)w2p;
    #pragma unroll
    for (int s = 0; s < 4; ++s) {
        bfrag B = bp2[(s * 8 + wid) * 64 + lane];
        #pragma unroll
        for (int rt = 0; rt < 4; ++rt) {
            int row = rt * 16 + lrow;
            bfrag av = *(const bfrag*)(tb + swz(row, s * 64 + lq * 16));
            acc2[rt] = MFMA(av, B, acc2[rt]);
        }
    }
    #pragma unroll
    for (int rt = 0; rt < 4; ++rt)
        #pragma unroll
        for (int r = 0; r < 4; ++r) {
            int row = rt * 16 + lq * 4 + r, col = wid * 16 + lrow;
            t2[row][col] = lrelu(acc2[rt][r] + bb2);
        }
    __syncthreads();
    if (threadIdx.x < 192) {
        int row = threadIdx.x & 63, c = threadIdx.x >> 6;
        float s = b3[c];
        #pragma unroll 4
        for (int k = 0; k < 128; ++k) s += t2[row][k] * W3[k * 3 + c];
        out[(size_t)(rowbase + row) * 3 + c] = 1.f / (1.f + expf(-s));
    }
}

// ---------------- small kernels ----------------
__global__ void k_vmin(const int* __restrict__ vx, int M, int* __restrict__ vmin) {
    __shared__ int sm[3 * 256];
    int t = threadIdx.x;
    int m0 = 0x7fffffff, m1 = 0x7fffffff, m2 = 0x7fffffff;
    for (int i = t; i < M; i += 256) {
        m0 = min(m0, vx[i * 3 + 0]); m1 = min(m1, vx[i * 3 + 1]); m2 = min(m2, vx[i * 3 + 2]);
    }
    sm[t] = m0; sm[256 + t] = m1; sm[512 + t] = m2;
    __syncthreads();
    for (int s = 128; s > 0; s >>= 1) {
        if (t < s) {
            sm[t] = min(sm[t], sm[t + s]);
            sm[256 + t] = min(sm[256 + t], sm[256 + t + s]);
            sm[512 + t] = min(sm[512 + t], sm[512 + t + s]);
        }
        __syncthreads();
    }
    if (t == 0) { vmin[0] = sm[0]; vmin[1] = sm[256]; vmin[2] = sm[512]; }
}

__global__ void k_scatter(const float* __restrict__ vf, const int* __restrict__ vx,
                          const int* __restrict__ vmin, float* __restrict__ g32, short* __restrict__ g16) {
    int m = blockIdx.x, j = threadIdx.x;
    int v0 = vx[m * 3 + 0] - vmin[0];
    int v1 = vx[m * 3 + 1] - vmin[1];
    int v2 = vx[m * 3 + 2] - vmin[2];
    size_t o = (size_t)(((v0 * GDIM) + v1) * GDIM + v2) * EF + j;
    float v = vf[(size_t)m * EF + j];
    g32[o] = v; g16[o] = f2b(v);
}

extern "C" void kernel_launch(void* const* d_in, const int* in_sizes, int n_in,
                              void* d_out, int out_size, void* d_ws, size_t ws_size,
                              hipStream_t stream) {
    const int*   pc_idx  = (const int*)  d_in[0];
    const float* pc_xyz  = (const float*)d_in[1];
    const int*   vox_int = (const int*)  d_in[2];
    const int*   vox_idx = (const int*)  d_in[3];
    const float* vox_xyz = (const float*)d_in[4];
    const float* pcf_W1  = (const float*)d_in[5];
    const float* pcf_b1  = (const float*)d_in[6];
    const float* pcf_W2  = (const float*)d_in[7];
    const float* pcf_b2  = (const float*)d_in[8];
    const float* pcres_W1 = (const float*)d_in[9];
    const float* pcres_b1 = (const float*)d_in[10];
    const float* pcres_W2 = (const float*)d_in[11];
    const float* pcres_b2 = (const float*)d_in[12];
    const float* pcc_W1  = (const float*)d_in[13];
    const float* pcc_b1  = (const float*)d_in[14];
    const float* pcc_W2  = (const float*)d_in[15];
    const float* pcc_b2  = (const float*)d_in[16];
    const float* r3_Wc1  = (const float*)d_in[17];
    const float* r3_bc1  = (const float*)d_in[18];
    const float* r3_Wc2  = (const float*)d_in[19];
    const float* r3_bc2  = (const float*)d_in[20];
    const float* lin1_W  = (const float*)d_in[21];
    const float* lin1_b  = (const float*)d_in[22];
    const float* lin2_W  = (const float*)d_in[23];
    const float* lin2_b  = (const float*)d_in[24];
    const float* linb_W  = (const float*)d_in[25];
    const float* linb_b  = (const float*)d_in[26];

    const size_t NE = (size_t)NPTS * EF;   // 4M elements
    float* A32 = (float*)d_ws;
    float* B32 = A32 + NE;
    short* A16 = (short*)(B32 + NE);
    short* B16 = A16 + NE;
    float* Y32 = (float*)(B16 + NE);
    short* Y16 = (short*)(Y32 + NE);
    short* pcf_w1p = Y16 + NE;                 // 1 step
    short* pcf_w2p = pcf_w1p + 1 * 4096;
    short* pcc_w1p = pcf_w2p + 4 * 4096;       // 6 layers x 5 steps
    short* pcc_w2p = pcc_w1p + 6 * 5 * 4096;   // 6 x 4
    short* pcr_w1p = pcc_w2p + 6 * 4 * 4096;   // 7 x 4
    short* pcr_w2p = pcr_w1p + 7 * 4 * 4096;
    short* wc2p    = pcr_w2p + 7 * 4 * 4096;   // 8 x 4
    short* lin1p   = wc2p    + 8 * 4 * 4096;
    short* lin2p   = lin1p   + 4 * 4096;
    short* wc1p    = lin2p   + 4 * 4096;       // 8 layers x 108 steps (pre-packed upfront)
    int*   vmin    = (int*)(wc1p + 8 * 108 * 4096);

    // ---- pack ALL weights upfront (batched: 10 launches total) ----
    k_pack_w<<<16, 256, 0, stream>>>(pcf_W1, pcf_w1p, 3, 1, 128, 1, 0, 0, 1);
    k_pack_w<<<64, 256, 0, stream>>>(pcf_W2, pcf_w2p, 128, 4, 128, 1, 0, 0, 1);
    k_pack_w<<<480, 256, 0, stream>>>(pcc_W1, pcc_w1p, 131, 5, 128, 1, 131 * 128, 5 * 4096, 6);
    k_pack_w<<<384, 256, 0, stream>>>(pcc_W2, pcc_w2p, 128, 4, 128, 1, 128 * 128, 4 * 4096, 6);
    k_pack_w<<<448, 256, 0, stream>>>(pcres_W1, pcr_w1p, 128, 4, 128, 1, 128 * 128, 4 * 4096, 7);
    k_pack_w<<<448, 256, 0, stream>>>(pcres_W2, pcr_w2p, 128, 4, 128, 1, 128 * 128, 4 * 4096, 7);
    k_pack_w<<<512, 256, 0, stream>>>(r3_Wc2, wc2p, 128, 4, 1, 128, 128 * 128, 4 * 4096, 8);
    k_pack_w<<<64, 256, 0, stream>>>(lin1_W, lin1p, 128, 4, 128, 1, 0, 0, 1);
    k_pack_w<<<64, 256, 0, stream>>>(lin2_W, lin2p, 128, 4, 128, 1, 0, 0, 1);
    k_pack_wc1<<<8 * 1728, 256, 0, stream>>>(r3_Wc1, wc1p);

    // ---- point-cloud stack with fused residual blocks (bf16 activations only) ----
    k_pcfirst<<<NPTS * KNN / 128, 512, 0, stream>>>(pc_xyz, pcf_w1p, pcf_b1, pcf_w2p, pcf_b2,
        pcr_w1p, pcres_b1, pcr_w2p, pcres_b2, nullptr, A16);
    short* cur16 = A16; short* nxt16 = B16;
    for (int i = 0; i < 5; ++i) {
        k_pcconv<<<NPTS * KNN / 128, 512, 0, stream>>>(cur16, pc_idx, pc_xyz,
            pcc_w1p + (size_t)i * 5 * 4096, pcc_b1 + i * EF,
            pcc_w2p + (size_t)i * 4 * 4096, pcc_b2 + i * EF,
            pcr_w1p + (size_t)(i + 1) * 4 * 4096, pcres_b1 + (i + 1) * EF,
            pcr_w2p + (size_t)(i + 1) * 4 * 4096, pcres_b2 + (i + 1) * EF,
            nullptr, nxt16);
        short* t = cur16; cur16 = nxt16; nxt16 = t;
    }
    // voxel layer: writes fp32 too (feeds the dense-grid scatter)
    k_pcconv<<<MVOX * KNN / 128, 512, 0, stream>>>(cur16, vox_idx, vox_xyz,
        pcc_w1p + (size_t)5 * 5 * 4096, pcc_b1 + 5 * EF,
        pcc_w2p + (size_t)5 * 4 * 4096, pcc_b2 + 5 * EF,
        pcr_w1p + (size_t)6 * 4 * 4096, pcres_b1 + 6 * EF,
        pcr_w2p + (size_t)6 * 4 * 4096, pcres_b2 + 6 * EF,
        A32, A16);   // voxfeat: fp32 in A32 rows 0..8191, bf16 in A16

    k_vmin<<<1, 256, 0, stream>>>(vox_int, MVOX, vmin);
    hipMemsetAsync(B32, 0, NE * sizeof(float), stream);
    hipMemsetAsync(B16, 0, NE * sizeof(short), stream);
    k_scatter<<<MVOX, 128, 0, stream>>>(A32, vox_int, vmin, B32, B16);

    // ---- 8 x resnet_block_rec3 (ping-pong B <-> Y), weights pre-packed ----
    float* cur32 = B32; short* curg = B16;
    float* nxt32 = Y32; short* nxtg = Y16;
    for (int i = 0; i < 8; ++i) {
        k_conv3<<<256, 512, 0, stream>>>(cur32, curg, wc1p + (size_t)i * 108 * 4096, r3_bc1 + i * EF,
                                         wc2p + (size_t)i * 4 * 4096, r3_bc2 + i * EF,
                                         nxt32, nxtg);
        float* t32 = cur32; cur32 = nxt32; nxt32 = t32;
        short* t16 = curg; curg = nxtg; nxtg = t16;
    }

    // ---- head ----
    k_head<<<MVOX / 64, 512, 0, stream>>>(curg, vox_int, vmin,
                                          lin1p, lin1_b, lin2p, lin2_b, linb_W, linb_b,
                                          (float*)d_out);
}

// Round 15
// 645.562 us; speedup vs baseline: 1.2825x; 1.0040x over previous
//
#include <hip/hip_runtime.h>
#include <math.h>

#define EF 128
#define NPTS 32768
#define KNN 8
#define MVOX 8192
#define GDIM 32
#define NVOXG (GDIM*GDIM*GDIM)

typedef __attribute__((ext_vector_type(8))) short bfrag;   // 8 x bf16
typedef __attribute__((ext_vector_type(4))) float f32x4;

__device__ __forceinline__ float lrelu(float x) { return x > 0.f ? x : 0.01f * x; }
__device__ __forceinline__ short f2b(float f) {            // fp32 -> bf16 (RNE)
    unsigned u = __float_as_uint(f);
    return (short)((u + 0x7fff + ((u >> 16) & 1)) >> 16);
}
#define MFMA(a,b,c) __builtin_amdgcn_mfma_f32_16x16x32_bf16((a),(b),(c),0,0,0)
// LDS tile addressing: row-major 256B rows, XOR swizzle on byte bits 4-6
__device__ __forceinline__ int swz(int row, int bytecol) {
    return row * 256 + (bytecol ^ ((row & 7) << 4));
}
// async global->LDS 16B DMA (no VGPR round-trip)
__device__ __forceinline__ void gload_lds16(const void* g, void* l) {
    __builtin_amdgcn_global_load_lds(
        (const __attribute__((address_space(1))) unsigned int*)g,
        (__attribute__((address_space(3))) unsigned int*)l, 16, 0, 0);
}

// ------- batched weight packing: n_layers x [W[k][col] -> [step][ct][lane][8] bf16] -------
__global__ void k_pack_w(const float* __restrict__ src, short* __restrict__ dst,
                         int K_real, int n_steps, int k_str, int c_str,
                         int src_ls, int dst_ls, int n_layers) {
    int t = blockIdx.x * 256 + threadIdx.x;
    int per = n_steps * 4096;
    if (t >= n_layers * per) return;
    int layer = t / per;
    int u = t - layer * per;
    int r = u & 7, l = (u >> 3) & 63, ct = (u >> 9) & 7, s = u >> 12;
    int k = s * 32 + (l >> 4) * 8 + r;
    int col = ct * 16 + (l & 15);
    float v = (k < K_real) ? src[(size_t)layer * src_ls + (size_t)k * k_str + (size_t)col * c_str] : 0.f;
    dst[(size_t)layer * dst_ls + u] = f2b(v);
}
// conv3x3x3 weights, 8 layers: [o][ci][27] -> [tap*4+cc][ct][lane][8]
__global__ void k_pack_wc1(const float* __restrict__ src, short* __restrict__ dst) {
    int g = blockIdx.x;
    int layer = g / 1728;
    int t = (g - layer * 1728) * 256 + threadIdx.x;
    if (t >= 108 * 4096) return;
    int r = t & 7, l = (t >> 3) & 63, ct = (t >> 9) & 7, s = t >> 12;
    int tap = s >> 2;
    int ci = (s & 3) * 32 + (l >> 4) * 8 + r;
    int col = ct * 16 + (l & 15);
    dst[(size_t)layer * 442368 + t] =
        f2b(src[(size_t)layer * 442368 + ((size_t)col * 128 + ci) * 27 + tap]);
}

// ============ template: block = 128 gather-rows (16 out rows), 8 waves 2Mx4N, fused res ============

// ---------------- pc_conv_first: MFMA phase-1 + GEMM2 + pool + fused res0 ----------------
__global__ __launch_bounds__(512) void k_pcfirst(
    const float* __restrict__ xyz, const short* __restrict__ w1p, const float* __restrict__ b1,
    const short* __restrict__ w2p, const float* __restrict__ b2,
    const short* __restrict__ rw1p, const float* __restrict__ rb1,
    const short* __restrict__ rw2p, const float* __restrict__ rb2,
    float* __restrict__ out32, short* __restrict__ out16) {
    __shared__ __align__(16) char tb[32768];
    int wid = threadIdx.x >> 6, lane = threadIdx.x & 63, lrow = lane & 15, lq = lane >> 4;
    int wm = wid >> 2, wn = wid & 3;
    int rowbase = blockIdx.x * 128;
    f32x4 zv = {0.f, 0.f, 0.f, 0.f};
    // ---- phase 1: 3->128 via 1-k-step MFMA ----
    {
        f32x4 acc1[4][2];
        #pragma unroll
        for (int rt = 0; rt < 4; ++rt) { acc1[rt][0] = zv; acc1[rt][1] = zv; }
        bfrag Bv[2];
        #pragma unroll
        for (int ct = 0; ct < 2; ++ct) Bv[ct] = ((const bfrag*)w1p)[(wn * 2 + ct) * 64 + lane];
        #pragma unroll
        for (int rt = 0; rt < 4; ++rt) {
            bfrag a4;
            #pragma unroll
            for (int r = 0; r < 8; ++r) a4[r] = 0;
            if (lq == 0) {
                int gr = rowbase + wm * 64 + rt * 16 + lrow;
                a4[0] = f2b(xyz[gr * 3]); a4[1] = f2b(xyz[gr * 3 + 1]); a4[2] = f2b(xyz[gr * 3 + 2]);
            }
            #pragma unroll
            for (int ct = 0; ct < 2; ++ct) acc1[rt][ct] = MFMA(a4, Bv[ct], acc1[rt][ct]);
        }
        float bb1[2];
        #pragma unroll
        for (int ct = 0; ct < 2; ++ct) bb1[ct] = b1[wn * 32 + ct * 16 + lrow];
        #pragma unroll
        for (int rt = 0; rt < 4; ++rt)
            #pragma unroll
            for (int ct = 0; ct < 2; ++ct)
                #pragma unroll
                for (int r = 0; r < 4; ++r) {
                    int row = wm * 64 + rt * 16 + lq * 4 + r, col = wn * 32 + ct * 16 + lrow;
                    *(short*)(tb + swz(row, col * 2)) = f2b(lrelu(acc1[rt][ct][r] + bb1[ct]));
                }
    }
    __syncthreads();
    // ---- GEMM2 + pool ----
    float bb2[2];
    #pragma unroll
    for (int ct = 0; ct < 2; ++ct) bb2[ct] = b2[wn * 32 + ct * 16 + lrow];
    f32x4 acc[4][2];
    #pragma unroll
    for (int rt = 0; rt < 4; ++rt) { acc[rt][0] = zv; acc[rt][1] = zv; }
    const bfrag* bp2 = (const bfrag*)w2p;
    #pragma unroll
    for (int s = 0; s < 4; ++s) {
        bfrag Bv[2];
        #pragma unroll
        for (int ct = 0; ct < 2; ++ct) Bv[ct] = bp2[(s * 8 + wn * 2 + ct) * 64 + lane];
        bfrag av[4];
        #pragma unroll
        for (int rt = 0; rt < 4; ++rt) {
            int row = wm * 64 + rt * 16 + lrow;
            av[rt] = *(const bfrag*)(tb + swz(row, s * 64 + lq * 16));
        }
        #pragma unroll
        for (int ct = 0; ct < 2; ++ct)
            #pragma unroll
            for (int rt = 0; rt < 4; ++rt) acc[rt][ct] = MFMA(av[rt], Bv[ct], acc[rt][ct]);
    }
    float pv[4][2];
    #pragma unroll
    for (int rt = 0; rt < 4; ++rt)
        #pragma unroll
        for (int ct = 0; ct < 2; ++ct) {
            float m = -INFINITY;
            #pragma unroll
            for (int r = 0; r < 4; ++r) m = fmaxf(m, acc[rt][ct][r] + bb2[ct]);
            m = fmaxf(m, __shfl_xor(m, 16, 64));
            pv[rt][ct] = lrelu(m);
        }
    // ---- pooled x -> LDS tiles ----
    __syncthreads();
    float* xf = (float*)(tb + 4096);            // [16][130]
    char*  tres = tb + 12544;                   // 16-row swizzled bf16 tile
    if ((lq & 1) == 0) {
        #pragma unroll
        for (int rt = 0; rt < 4; ++rt)
            #pragma unroll
            for (int ct = 0; ct < 2; ++ct) {
                int row = wm * 8 + rt * 2 + (lq >> 1), col = wn * 32 + ct * 16 + lrow;
                *(short*)(tb + swz(row, col * 2)) = f2b(pv[rt][ct]);
                xf[row * 130 + col] = pv[rt][ct];
            }
    }
    __syncthreads();
    // ---- fused res: GEMM1 ----
    {
        f32x4 r1 = zv;
        #pragma unroll
        for (int s = 0; s < 4; ++s) {
            bfrag B = ((const bfrag*)rw1p)[(s * 8 + wid) * 64 + lane];
            bfrag a = *(const bfrag*)(tb + swz(lrow, s * 64 + lq * 16));
            r1 = MFMA(a, B, r1);
        }
        float rb1v = rb1[wid * 16 + lrow];
        #pragma unroll
        for (int r = 0; r < 4; ++r) {
            int row = lq * 4 + r;
            *(short*)(tres + swz(row, (wid * 16 + lrow) * 2)) = f2b(lrelu(r1[r] + rb1v));
        }
    }
    __syncthreads();
    {
        f32x4 r2 = zv;
        #pragma unroll
        for (int s = 0; s < 4; ++s) {
            bfrag B = ((const bfrag*)rw2p)[(s * 8 + wid) * 64 + lane];
            bfrag a = *(const bfrag*)(tres + swz(lrow, s * 64 + lq * 16));
            r2 = MFMA(a, B, r2);
        }
        float rb2v = rb2[wid * 16 + lrow];
        int p0 = blockIdx.x * 16;
        #pragma unroll
        for (int r = 0; r < 4; ++r) {
            int row = lq * 4 + r, col = wid * 16 + lrow;
            float v = lrelu(r2[r] + rb2v + xf[row * 130 + col]);
            size_t o = (size_t)(p0 + row) * 128 + col;
            out16[o] = f2b(v);
            if (out32) out32[o] = v;
        }
    }
}

// ---------------- pc_conv: staged gather + 131->128 + 128->128 + pool + fused res ----------------
__global__ __launch_bounds__(512) void k_pcconv(
    const short* __restrict__ fin16, const int* __restrict__ idx, const float* __restrict__ xyz,
    const short* __restrict__ w1p, const float* __restrict__ b1,
    const short* __restrict__ w2p, const float* __restrict__ b2,
    const short* __restrict__ rw1p, const float* __restrict__ rb1,
    const short* __restrict__ rw2p, const float* __restrict__ rb2,
    float* __restrict__ out32, short* __restrict__ out16) {
    __shared__ __align__(16) char tb[32768];
    int wid = threadIdx.x >> 6, lane = threadIdx.x & 63, lrow = lane & 15, lq = lane >> 4;
    int wm = wid >> 2, wn = wid & 3;
    int rowbase = blockIdx.x * 128;
    f32x4 zv = {0.f, 0.f, 0.f, 0.f};
    // stage gathered rows once per block
    {
        int srow = threadIdx.x >> 2, sseg = threadIdx.x & 3;
        int nb = idx[rowbase + srow];
        const bfrag* src = (const bfrag*)(fin16 + (size_t)nb * 128);
        #pragma unroll
        for (int j = 0; j < 4; ++j) {
            int seg = sseg + j * 4;
            bfrag v = src[seg];
            *(bfrag*)(tb + swz(srow, seg * 16)) = v;
        }
    }
    __syncthreads();
    float bb1[2], bb2[2];
    #pragma unroll
    for (int ct = 0; ct < 2; ++ct) {
        bb1[ct] = b1[wn * 32 + ct * 16 + lrow];
        bb2[ct] = b2[wn * 32 + ct * 16 + lrow];
    }
    f32x4 acc[4][2];
    #pragma unroll
    for (int rt = 0; rt < 4; ++rt) { acc[rt][0] = zv; acc[rt][1] = zv; }
    const bfrag* bp1 = (const bfrag*)w1p;
    #pragma unroll
    for (int s = 0; s < 4; ++s) {
        bfrag Bv[2];
        #pragma unroll
        for (int ct = 0; ct < 2; ++ct) Bv[ct] = bp1[(s * 8 + wn * 2 + ct) * 64 + lane];
        bfrag av[4];
        #pragma unroll
        for (int rt = 0; rt < 4; ++rt) {
            int row = wm * 64 + rt * 16 + lrow;
            av[rt] = *(const bfrag*)(tb + swz(row, s * 64 + lq * 16));
        }
        #pragma unroll
        for (int ct = 0; ct < 2; ++ct)
            #pragma unroll
            for (int rt = 0; rt < 4; ++rt) acc[rt][ct] = MFMA(av[rt], Bv[ct], acc[rt][ct]);
    }
    {   // k-step 4: xyz concat (cols 128..130)
        bfrag Bv[2];
        #pragma unroll
        for (int ct = 0; ct < 2; ++ct) Bv[ct] = bp1[(32 + wn * 2 + ct) * 64 + lane];
        #pragma unroll
        for (int rt = 0; rt < 4; ++rt) {
            bfrag a4;
            #pragma unroll
            for (int r = 0; r < 8; ++r) a4[r] = 0;
            if (lq == 0) {
                int gr = rowbase + wm * 64 + rt * 16 + lrow;
                a4[0] = f2b(xyz[gr * 3]); a4[1] = f2b(xyz[gr * 3 + 1]); a4[2] = f2b(xyz[gr * 3 + 2]);
            }
            #pragma unroll
            for (int ct = 0; ct < 2; ++ct) acc[rt][ct] = MFMA(a4, Bv[ct], acc[rt][ct]);
        }
    }
    __syncthreads();   // all GEMM1 reads of tb done before overwrite
    #pragma unroll
    for (int rt = 0; rt < 4; ++rt)
        #pragma unroll
        for (int ct = 0; ct < 2; ++ct)
            #pragma unroll
            for (int r = 0; r < 4; ++r) {
                int row = wm * 64 + rt * 16 + lq * 4 + r, col = wn * 32 + ct * 16 + lrow;
                *(short*)(tb + swz(row, col * 2)) = f2b(lrelu(acc[rt][ct][r] + bb1[ct]));
            }
    __syncthreads();
    f32x4 acc2[4][2];
    #pragma unroll
    for (int rt = 0; rt < 4; ++rt) { acc2[rt][0] = zv; acc2[rt][1] = zv; }
    const bfrag* bp2 = (const bfrag*)w2p;
    #pragma unroll
    for (int s = 0; s < 4; ++s) {
        bfrag Bv[2];
        #pragma unroll
        for (int ct = 0; ct < 2; ++ct) Bv[ct] = bp2[(s * 8 + wn * 2 + ct) * 64 + lane];
        bfrag av[4];
        #pragma unroll
        for (int rt = 0; rt < 4; ++rt) {
            int row = wm * 64 + rt * 16 + lrow;
            av[rt] = *(const bfrag*)(tb + swz(row, s * 64 + lq * 16));
        }
        #pragma unroll
        for (int ct = 0; ct < 2; ++ct)
            #pragma unroll
            for (int rt = 0; rt < 4; ++rt) acc2[rt][ct] = MFMA(av[rt], Bv[ct], acc2[rt][ct]);
    }
    float pv[4][2];
    #pragma unroll
    for (int rt = 0; rt < 4; ++rt)
        #pragma unroll
        for (int ct = 0; ct < 2; ++ct) {
            float m = -INFINITY;
            #pragma unroll
            for (int r = 0; r < 4; ++r) m = fmaxf(m, acc2[rt][ct][r] + bb2[ct]);
            m = fmaxf(m, __shfl_xor(m, 16, 64));
            pv[rt][ct] = lrelu(m);
        }
    // ---- pooled x -> LDS tiles ----
    __syncthreads();
    float* xf = (float*)(tb + 4096);            // [16][130]
    char*  tres = tb + 12544;
    if ((lq & 1) == 0) {
        #pragma unroll
        for (int rt = 0; rt < 4; ++rt)
            #pragma unroll
            for (int ct = 0; ct < 2; ++ct) {
                int row = wm * 8 + rt * 2 + (lq >> 1), col = wn * 32 + ct * 16 + lrow;
                *(short*)(tb + swz(row, col * 2)) = f2b(pv[rt][ct]);
                xf[row * 130 + col] = pv[rt][ct];
            }
    }
    __syncthreads();
    // ---- fused res ----
    {
        f32x4 r1 = zv;
        #pragma unroll
        for (int s = 0; s < 4; ++s) {
            bfrag B = ((const bfrag*)rw1p)[(s * 8 + wid) * 64 + lane];
            bfrag a = *(const bfrag*)(tb + swz(lrow, s * 64 + lq * 16));
            r1 = MFMA(a, B, r1);
        }
        float rb1v = rb1[wid * 16 + lrow];
        #pragma unroll
        for (int r = 0; r < 4; ++r) {
            int row = lq * 4 + r;
            *(short*)(tres + swz(row, (wid * 16 + lrow) * 2)) = f2b(lrelu(r1[r] + rb1v));
        }
    }
    __syncthreads();
    {
        f32x4 r2 = zv;
        #pragma unroll
        for (int s = 0; s < 4; ++s) {
            bfrag B = ((const bfrag*)rw2p)[(s * 8 + wid) * 64 + lane];
            bfrag a = *(const bfrag*)(tres + swz(lrow, s * 64 + lq * 16));
            r2 = MFMA(a, B, r2);
        }
        float rb2v = rb2[wid * 16 + lrow];
        int p0 = blockIdx.x * 16;
        #pragma unroll
        for (int r = 0; r < 4; ++r) {
            int row = lq * 4 + r, col = wid * 16 + lrow;
            float v = lrelu(r2[r] + rb2v + xf[row * 130 + col]);
            size_t o = (size_t)(p0 + row) * 128 + col;
            out16[o] = f2b(v);
            if (out32) out32[o] = v;
        }
    }
}

// ---------------- conv3d 3x3x3: R12 compute + async dbuf slab staging via global_load_lds ----------------
// block M128, 8 waves 2Mx2Nx2K (wave M64xN64xK64); LDS dest linear, source pre-swizzled; OOB -> zero page
__global__ __launch_bounds__(512) void k_conv3(
    const float* __restrict__ gin32, const short* __restrict__ gin16,
    const short* __restrict__ zeros,
    const short* __restrict__ w1p, const float* __restrict__ b1,
    const short* __restrict__ w2p, const float* __restrict__ b2,
    float* __restrict__ gout32, short* __restrict__ gout16) {
    __shared__ __align__(16) char Ab[98304];    // 2 x 48KB slab dbuf; epilogue reuses [0,96K)
    int wid = threadIdx.x >> 6, lane = threadIdx.x & 63, lrow = lane & 15, lq = lane >> 4;
    int kg = wid & 1, wn = (wid >> 1) & 1, wm = wid >> 2;
    int va = blockIdx.x >> 3, vb0 = (blockIdx.x & 7) * 4;
    bfrag zf;
    #pragma unroll
    for (int r = 0; r < 8; ++r) zf[r] = 0;
    f32x4 zv = {0.f, 0.f, 0.f, 0.f};
    f32x4 acc[4][4];
    #pragma unroll
    for (int rt = 0; rt < 4; ++rt)
        #pragma unroll
        for (int ct = 0; ct < 4; ++ct) acc[rt][ct] = zv;
    const bfrag* bp1 = (const bfrag*)w1p;

    // per-thread staging geometry (6 x 16B per thread covers 192 rows x 256B)
    int tsk0 = (int)threadIdx.x;
    // issue slab for a-plane `aa` into buffer `buf` (async DMA, branchless source select)
    #define ISSUE_SLAB(aa_, buf_)                                                           \
        {                                                                                   \
            int aa = (aa_);                                                                 \
            bool aok = (unsigned)aa < 32u;                                                  \
            _Pragma("unroll")                                                               \
            for (int j = 0; j < 6; ++j) {                                                   \
                int task = tsk0 + j * 512;                                                  \
                int srow = task >> 4, segl = task & 15;                                     \
                int bl = srow >> 5, c = srow & 31;                                          \
                int sb = vb0 - 1 + bl;                                                      \
                int segg = segl ^ (srow & 7);                                               \
                bool ok = aok && ((unsigned)sb < 32u);                                      \
                const short* gsrc = ok ? (gin16 + (size_t)((aa * 32 + sb) * 32 + c) * 128 + segg * 8) \
                                       : (zeros + segg * 8);                                \
                gload_lds16(gsrc, Ab + (buf_) * 49152 + (size_t)task * 16);                 \
            }                                                                               \
        }

    // prologue: stage slab da=-1 into buffer 0
    ISSUE_SLAB(va - 1, 0)
    __syncthreads();                             // drains vmcnt, slab 0 ready

    #pragma unroll 1
    for (int dai = 0; dai < 3; ++dai) {
        // issue-early: next slab DMA into other buffer (in flight under 288 MFMAs, no VGPR cost)
        if (dai < 2) ISSUE_SLAB(va + dai, (dai + 1) & 1)
        // compute current slab: 9 taps x 2 k-subslices, B loads at point of use (R12-exact)
        const char* slab = Ab + (dai & 1) * 49152;
        #pragma unroll
        for (int t9 = 0; t9 < 9; ++t9) {
            int db = t9 / 3 - 1, dc = t9 % 3 - 1;
            int tap = dai * 9 + t9;
            #pragma unroll
            for (int ss = 0; ss < 2; ++ss) {
                int s = kg * 2 + ss;
                bfrag Bv[4];
                #pragma unroll
                for (int ct = 0; ct < 4; ++ct)
                    Bv[ct] = bp1[((tap * 4 + s) * 8 + wn * 4 + ct) * 64 + lane];
                bfrag av[4];
                #pragma unroll
                for (int rt = 0; rt < 4; ++rt) {
                    int ci = ((rt & 1) << 4) + lrow + dc;
                    bool ok = (unsigned)ci < 32u;
                    int srow2 = (wm * 2 + db + 1 + (rt >> 1)) * 32 + (ok ? ci : 0);
                    bfrag t = *(const bfrag*)(slab + swz(srow2, s * 64 + lq * 16));
                    av[rt] = ok ? t : zf;
                }
                #pragma unroll
                for (int ct = 0; ct < 4; ++ct)
                    #pragma unroll
                    for (int rt = 0; rt < 4; ++rt) acc[rt][ct] = MFMA(av[rt], Bv[ct], acc[rt][ct]);
            }
        }
        __syncthreads();                         // drains DMA for next slab + all reads done
    }
    #undef ISSUE_SLAB

    // ---- k-reduce: kg=1 dumps at [0..64KB); kg=0 sums ----
    if (kg == 1) {
        int p = wm * 2 + wn;
        #pragma unroll
        for (int rt = 0; rt < 4; ++rt)
            #pragma unroll
            for (int ct = 0; ct < 4; ++ct)
                *(f32x4*)(Ab + p * 16384 + ((rt * 4 + ct) * 64 + lane) * 16) = acc[rt][ct];
    }
    __syncthreads();
    if (kg == 0) {
        int p = wm * 2 + wn;
        #pragma unroll
        for (int rt = 0; rt < 4; ++rt)
            #pragma unroll
            for (int ct = 0; ct < 4; ++ct)
                acc[rt][ct] += *(const f32x4*)(Ab + p * 16384 + ((rt * 4 + ct) * 64 + lane) * 16);
    }
    __syncthreads();
    // ---- kg=0 waves write bias+lrelu t-tile (128 rows x 256 B) ----
    if (kg == 0) {
        float bb1[4];
        #pragma unroll
        for (int ct = 0; ct < 4; ++ct) bb1[ct] = b1[wn * 64 + ct * 16 + lrow];
        #pragma unroll
        for (int rt = 0; rt < 4; ++rt)
            #pragma unroll
            for (int ct = 0; ct < 4; ++ct)
                #pragma unroll
                for (int r = 0; r < 4; ++r) {
                    int row = wm * 64 + rt * 16 + lq * 4 + r, col = wn * 64 + ct * 16 + lrow;
                    *(short*)(Ab + swz(row, col * 2)) = f2b(lrelu(acc[rt][ct][r] + bb1[ct]));
                }
    }
    __syncthreads();
    // ---- fused 1x1 + residual: all 8 waves as 2M x 4N (wave M64 x N32) ----
    int wm2 = wid >> 2, wn2 = wid & 3;
    float bb2[2];
    #pragma unroll
    for (int ct = 0; ct < 2; ++ct) bb2[ct] = b2[wn2 * 32 + ct * 16 + lrow];
    f32x4 acc2[4][2];
    #pragma unroll
    for (int rt = 0; rt < 4; ++rt) { acc2[rt][0] = zv; acc2[rt][1] = zv; }
    const bfrag* bp2 = (const bfrag*)w2p;
    #pragma unroll
    for (int s = 0; s < 4; ++s) {
        bfrag Bv[2];
        #pragma unroll
        for (int ct = 0; ct < 2; ++ct) Bv[ct] = bp2[(s * 8 + wn2 * 2 + ct) * 64 + lane];
        bfrag av[4];
        #pragma unroll
        for (int rt = 0; rt < 4; ++rt) {
            int row = wm2 * 64 + rt * 16 + lrow;
            av[rt] = *(const bfrag*)(Ab + swz(row, s * 64 + lq * 16));
        }
        #pragma unroll
        for (int ct = 0; ct < 2; ++ct)
            #pragma unroll
            for (int rt = 0; rt < 4; ++rt) acc2[rt][ct] = MFMA(av[rt], Bv[ct], acc2[rt][ct]);
    }
    #pragma unroll
    for (int rt = 0; rt < 4; ++rt)
        #pragma unroll
        for (int ct = 0; ct < 2; ++ct)
            #pragma unroll
            for (int r = 0; r < 4; ++r) {
                int row = wm2 * 64 + rt * 16 + lq * 4 + r;
                int voxel = (va * 32 + vb0 + (row >> 5)) * 32 + (row & 31);
                size_t o = (size_t)voxel * 128 + wn2 * 32 + ct * 16 + lrow;
                float v = lrelu(acc2[rt][ct][r] + bb2[ct] + gin32[o]);
                gout32[o] = v; gout16[o] = f2b(v);
            }
}

// ---------------- head: gather + lin1 + lin2 + linb + sigmoid; block M64, 8 waves ----------------
__global__ __launch_bounds__(512) void k_head(
    const short* __restrict__ g16, const int* __restrict__ vx, const int* __restrict__ vmin,
    const short* __restrict__ w1p, const float* __restrict__ b1,
    const short* __restrict__ w2p, const float* __restrict__ b2,
    const float* __restrict__ W3, const float* __restrict__ b3,
    float* __restrict__ out) {
    __shared__ __align__(16) char tb[16384];
    __shared__ float t2[64][129];
    int wid = threadIdx.x >> 6, lane = threadIdx.x & 63, lrow = lane & 15, lq = lane >> 4;
    int rowbase = blockIdx.x * 64;
    int goff[4];
    #pragma unroll
    for (int rt = 0; rt < 4; ++rt) {
        int m = rowbase + rt * 16 + lrow;
        int v0 = vx[m * 3 + 0] - vmin[0];
        int v1 = vx[m * 3 + 1] - vmin[1];
        int v2 = vx[m * 3 + 2] - vmin[2];
        goff[rt] = ((v0 * 32 + v1) * 32 + v2) * 128;
    }
    float bb1 = b1[wid * 16 + lrow], bb2 = b2[wid * 16 + lrow];
    f32x4 zv = {0.f, 0.f, 0.f, 0.f};
    f32x4 acc[4];
    #pragma unroll
    for (int rt = 0; rt < 4; ++rt) acc[rt] = zv;
    const bfrag* bp1 = (const bfrag*)w1p;
    #pragma unroll
    for (int s = 0; s < 4; ++s) {
        bfrag B = bp1[(s * 8 + wid) * 64 + lane];
        #pragma unroll
        for (int rt = 0; rt < 4; ++rt) {
            bfrag a = *((const bfrag*)(g16 + goff[rt]) + s * 4 + lq);
            acc[rt] = MFMA(a, B, acc[rt]);
        }
    }
    #pragma unroll
    for (int rt = 0; rt < 4; ++rt)
        #pragma unroll
        for (int r = 0; r < 4; ++r) {
            int row = rt * 16 + lq * 4 + r, col = wid * 16 + lrow;
            *(short*)(tb + swz(row, col * 2)) = f2b(lrelu(acc[rt][r] + bb1));
        }
    __syncthreads();
    f32x4 acc2[4];
    #pragma unroll
    for (int rt = 0; rt < 4; ++rt) acc2[rt] = zv;
    const bfrag* bp2 = (const bfrag*)w2p;
    #pragma unroll
    for (int s = 0; s < 4; ++s) {
        bfrag B = bp2[(s * 8 + wid) * 64 + lane];
        #pragma unroll
        for (int rt = 0; rt < 4; ++rt) {
            int row = rt * 16 + lrow;
            bfrag av = *(const bfrag*)(tb + swz(row, s * 64 + lq * 16));
            acc2[rt] = MFMA(av, B, acc2[rt]);
        }
    }
    #pragma unroll
    for (int rt = 0; rt < 4; ++rt)
        #pragma unroll
        for (int r = 0; r < 4; ++r) {
            int row = rt * 16 + lq * 4 + r, col = wid * 16 + lrow;
            t2[row][col] = lrelu(acc2[rt][r] + bb2);
        }
    __syncthreads();
    if (threadIdx.x < 192) {
        int row = threadIdx.x & 63, c = threadIdx.x >> 6;
        float s = b3[c];
        #pragma unroll 4
        for (int k = 0; k < 128; ++k) s += t2[row][k] * W3[k * 3 + c];
        out[(size_t)(rowbase + row) * 3 + c] = 1.f / (1.f + expf(-s));
    }
}

// ---------------- small kernels ----------------
__global__ void k_vmin(const int* __restrict__ vx, int M, int* __restrict__ vmin) {
    __shared__ int sm[3 * 256];
    int t = threadIdx.x;
    int m0 = 0x7fffffff, m1 = 0x7fffffff, m2 = 0x7fffffff;
    for (int i = t; i < M; i += 256) {
        m0 = min(m0, vx[i * 3 + 0]); m1 = min(m1, vx[i * 3 + 1]); m2 = min(m2, vx[i * 3 + 2]);
    }
    sm[t] = m0; sm[256 + t] = m1; sm[512 + t] = m2;
    __syncthreads();
    for (int s = 128; s > 0; s >>= 1) {
        if (t < s) {
            sm[t] = min(sm[t], sm[t + s]);
            sm[256 + t] = min(sm[256 + t], sm[256 + t + s]);
            sm[512 + t] = min(sm[512 + t], sm[512 + t + s]);
        }
        __syncthreads();
    }
    if (t == 0) { vmin[0] = sm[0]; vmin[1] = sm[256]; vmin[2] = sm[512]; }
}

__global__ void k_scatter(const float* __restrict__ vf, const int* __restrict__ vx,
                          const int* __restrict__ vmin, float* __restrict__ g32, short* __restrict__ g16) {
    int m = blockIdx.x, j = threadIdx.x;
    int v0 = vx[m * 3 + 0] - vmin[0];
    int v1 = vx[m * 3 + 1] - vmin[1];
    int v2 = vx[m * 3 + 2] - vmin[2];
    size_t o = (size_t)(((v0 * GDIM) + v1) * GDIM + v2) * EF + j;
    float v = vf[(size_t)m * EF + j];
    g32[o] = v; g16[o] = f2b(v);
}

extern "C" void kernel_launch(void* const* d_in, const int* in_sizes, int n_in,
                              void* d_out, int out_size, void* d_ws, size_t ws_size,
                              hipStream_t stream) {
    const int*   pc_idx  = (const int*)  d_in[0];
    const float* pc_xyz  = (const float*)d_in[1];
    const int*   vox_int = (const int*)  d_in[2];
    const int*   vox_idx = (const int*)  d_in[3];
    const float* vox_xyz = (const float*)d_in[4];
    const float* pcf_W1  = (const float*)d_in[5];
    const float* pcf_b1  = (const float*)d_in[6];
    const float* pcf_W2  = (const float*)d_in[7];
    const float* pcf_b2  = (const float*)d_in[8];
    const float* pcres_W1 = (const float*)d_in[9];
    const float* pcres_b1 = (const float*)d_in[10];
    const float* pcres_W2 = (const float*)d_in[11];
    const float* pcres_b2 = (const float*)d_in[12];
    const float* pcc_W1  = (const float*)d_in[13];
    const float* pcc_b1  = (const float*)d_in[14];
    const float* pcc_W2  = (const float*)d_in[15];
    const float* pcc_b2  = (const float*)d_in[16];
    const float* r3_Wc1  = (const float*)d_in[17];
    const float* r3_bc1  = (const float*)d_in[18];
    const float* r3_Wc2  = (const float*)d_in[19];
    const float* r3_bc2  = (const float*)d_in[20];
    const float* lin1_W  = (const float*)d_in[21];
    const float* lin1_b  = (const float*)d_in[22];
    const float* lin2_W  = (const float*)d_in[23];
    const float* lin2_b  = (const float*)d_in[24];
    const float* linb_W  = (const float*)d_in[25];
    const float* linb_b  = (const float*)d_in[26];

    const size_t NE = (size_t)NPTS * EF;   // 4M elements
    float* A32 = (float*)d_ws;
    float* B32 = A32 + NE;
    short* A16 = (short*)(B32 + NE);
    short* B16 = A16 + NE;
    float* Y32 = (float*)(B16 + NE);
    short* Y16 = (short*)(Y32 + NE);
    short* pcf_w1p = Y16 + NE;                 // 1 step
    short* pcf_w2p = pcf_w1p + 1 * 4096;
    short* pcc_w1p = pcf_w2p + 4 * 4096;       // 6 layers x 5 steps
    short* pcc_w2p = pcc_w1p + 6 * 5 * 4096;   // 6 x 4
    short* pcr_w1p = pcc_w2p + 6 * 4 * 4096;   // 7 x 4
    short* pcr_w2p = pcr_w1p + 7 * 4 * 4096;
    short* wc2p    = pcr_w2p + 7 * 4 * 4096;   // 8 x 4
    short* lin1p   = wc2p    + 8 * 4 * 4096;
    short* lin2p   = lin1p   + 4 * 4096;
    short* wc1p    = lin2p   + 4 * 4096;       // 8 layers x 108 steps (pre-packed upfront)
    short* zbuf    = wc1p + 8 * 108 * 4096;    // 4KB zero page for conv3 halo DMA
    int*   vmin    = (int*)(zbuf + 2048);

    // ---- zero page for conv3 OOB DMA redirect ----
    hipMemsetAsync(zbuf, 0, 4096, stream);

    // ---- pack ALL weights upfront (batched: 10 launches total) ----
    k_pack_w<<<16, 256, 0, stream>>>(pcf_W1, pcf_w1p, 3, 1, 128, 1, 0, 0, 1);
    k_pack_w<<<64, 256, 0, stream>>>(pcf_W2, pcf_w2p, 128, 4, 128, 1, 0, 0, 1);
    k_pack_w<<<480, 256, 0, stream>>>(pcc_W1, pcc_w1p, 131, 5, 128, 1, 131 * 128, 5 * 4096, 6);
    k_pack_w<<<384, 256, 0, stream>>>(pcc_W2, pcc_w2p, 128, 4, 128, 1, 128 * 128, 4 * 4096, 6);
    k_pack_w<<<448, 256, 0, stream>>>(pcres_W1, pcr_w1p, 128, 4, 128, 1, 128 * 128, 4 * 4096, 7);
    k_pack_w<<<448, 256, 0, stream>>>(pcres_W2, pcr_w2p, 128, 4, 128, 1, 128 * 128, 4 * 4096, 7);
    k_pack_w<<<512, 256, 0, stream>>>(r3_Wc2, wc2p, 128, 4, 1, 128, 128 * 128, 4 * 4096, 8);
    k_pack_w<<<64, 256, 0, stream>>>(lin1_W, lin1p, 128, 4, 128, 1, 0, 0, 1);
    k_pack_w<<<64, 256, 0, stream>>>(lin2_W, lin2p, 128, 4, 128, 1, 0, 0, 1);
    k_pack_wc1<<<8 * 1728, 256, 0, stream>>>(r3_Wc1, wc1p);

    // ---- point-cloud stack with fused residual blocks (bf16 activations only) ----
    k_pcfirst<<<NPTS * KNN / 128, 512, 0, stream>>>(pc_xyz, pcf_w1p, pcf_b1, pcf_w2p, pcf_b2,
        pcr_w1p, pcres_b1, pcr_w2p, pcres_b2, nullptr, A16);
    short* cur16 = A16; short* nxt16 = B16;
    for (int i = 0; i < 5; ++i) {
        k_pcconv<<<NPTS * KNN / 128, 512, 0, stream>>>(cur16, pc_idx, pc_xyz,
            pcc_w1p + (size_t)i * 5 * 4096, pcc_b1 + i * EF,
            pcc_w2p + (size_t)i * 4 * 4096, pcc_b2 + i * EF,
            pcr_w1p + (size_t)(i + 1) * 4 * 4096, pcres_b1 + (i + 1) * EF,
            pcr_w2p + (size_t)(i + 1) * 4 * 4096, pcres_b2 + (i + 1) * EF,
            nullptr, nxt16);
        short* t = cur16; cur16 = nxt16; nxt16 = t;
    }
    // voxel layer: writes fp32 too (feeds the dense-grid scatter)
    k_pcconv<<<MVOX * KNN / 128, 512, 0, stream>>>(cur16, vox_idx, vox_xyz,
        pcc_w1p + (size_t)5 * 5 * 4096, pcc_b1 + 5 * EF,
        pcc_w2p + (size_t)5 * 4 * 4096, pcc_b2 + 5 * EF,
        pcr_w1p + (size_t)6 * 4 * 4096, pcres_b1 + 6 * EF,
        pcr_w2p + (size_t)6 * 4 * 4096, pcres_b2 + 6 * EF,
        A32, A16);   // voxfeat: fp32 in A32 rows 0..8191, bf16 in A16

    k_vmin<<<1, 256, 0, stream>>>(vox_int, MVOX, vmin);
    hipMemsetAsync(B32, 0, NE * sizeof(float), stream);
    hipMemsetAsync(B16, 0, NE * sizeof(short), stream);
    k_scatter<<<MVOX, 128, 0, stream>>>(A32, vox_int, vmin, B32, B16);

    // ---- 8 x resnet_block_rec3 (ping-pong B <-> Y), weights pre-packed ----
    float* cur32 = B32; short* curg = B16;
    float* nxt32 = Y32; short* nxtg = Y16;
    for (int i = 0; i < 8; ++i) {
        k_conv3<<<256, 512, 0, stream>>>(cur32, curg, zbuf,
                                         wc1p + (size_t)i * 108 * 4096, r3_bc1 + i * EF,
                                         wc2p + (size_t)i * 4 * 4096, r3_bc2 + i * EF,
                                         nxt32, nxtg);
        float* t32 = cur32; cur32 = nxt32; nxt32 = t32;
        short* t16 = curg; curg = nxtg; nxtg = t16;
    }

    // ---- head ----
    k_head<<<MVOX / 64, 512, 0, stream>>>(curg, vox_int, vmin,
                                          lin1p, lin1_b, lin2p, lin2_b, linb_W, linb_b,
                                          (float*)d_out);
}